// Round 5
// baseline (781.507 us; speedup 1.0000x reference)
//
#include <hip/hip_runtime.h>

typedef unsigned short u16;
typedef _Float16 f16x8 __attribute__((ext_vector_type(8)));
typedef float f32x4 __attribute__((ext_vector_type(4)));
typedef u16 u16x8 __attribute__((ext_vector_type(8)));

#define MINF (-0x1.fffffep+127f)
#define SCALE 0.08838834764831845f

__device__ __forceinline__ u16 f2h(float f) {
    _Float16 h = (_Float16)f;
    return __builtin_bit_cast(u16, h);
}
__device__ __forceinline__ float h2f(u16 u) {
    _Float16 h = __builtin_bit_cast(_Float16, u);
    return (float)h;
}

typedef const __attribute__((address_space(1))) void* gptr_t;
typedef __attribute__((address_space(3))) void* sptr_t;
#define GLDS16(g, l) __builtin_amdgcn_global_load_lds((gptr_t)(const void*)(g), (sptr_t)(void*)(l), 16, 0, 0)

// ---------------- f32 -> f16 conversion, 8 elem/thread (n must be divisible by 2048) ----------------
__global__ void convk8(const float* __restrict__ in, u16* __restrict__ out, int n) {
    int i = (blockIdx.x * 256 + threadIdx.x) * 8;
    if (i >= n) return;
    f32x4 a = *(const f32x4*)&in[i];
    f32x4 b = *(const f32x4*)&in[i + 4];
    u16x8 r;
#pragma unroll
    for (int j = 0; j < 4; ++j) { r[j] = f2h(a[j]); r[j + 4] = f2h(b[j]); }
    *(u16x8*)&out[i] = r;
}

// ---------------- GEMM C = A * Bw^T  (A: MxK row-major f16, Bw: NxK row-major f16) ----------------
// EPI=0: write f32 C (N param). EPI=1: QKV scatter epilogue (N=4096).
template <int EPI>
__global__ __launch_bounds__(256) void gemm_bt(
    const u16* __restrict__ A, const u16* __restrict__ Bw, float* __restrict__ Cf,
    u16* __restrict__ qo, u16* __restrict__ ko, u16* __restrict__ vto, int N, int K) {
    __shared__ alignas(16) u16 As[128 * 32];
    __shared__ alignas(16) u16 Bs[128 * 32];
    int tid = threadIdx.x;
    int wid = tid >> 6, lane = tid & 63;
    int l16 = lane & 15, lhi = lane >> 4;
    int bm = blockIdx.y * 128, bn = blockIdx.x * 128;
    int wr = (wid >> 1) * 64, wc = (wid & 1) * 64;
    int srow = lane >> 2, sseg = lane & 3;
    f32x4 acc[4][4] = {};
    for (int kt = 0; kt < K; kt += 32) {
        __syncthreads();
#pragma unroll
        for (int i = 0; i < 2; ++i) {
            const u16* ga = A + (size_t)(bm + i * 64 + wid * 16 + srow) * K + kt + sseg * 8;
            GLDS16(ga, &As[(i * 64 + wid * 16) * 32]);
            const u16* gb = Bw + (size_t)(bn + i * 64 + wid * 16 + srow) * K + kt + sseg * 8;
            GLDS16(gb, &Bs[(i * 64 + wid * 16) * 32]);
        }
        __syncthreads();
        f16x8 af[4], bf[4];
#pragma unroll
        for (int mi = 0; mi < 4; ++mi) af[mi] = *(const f16x8*)&As[(wr + mi * 16 + l16) * 32 + lhi * 8];
#pragma unroll
        for (int ni = 0; ni < 4; ++ni) bf[ni] = *(const f16x8*)&Bs[(wc + ni * 16 + l16) * 32 + lhi * 8];
#pragma unroll
        for (int mi = 0; mi < 4; ++mi)
#pragma unroll
            for (int ni = 0; ni < 4; ++ni)
                acc[mi][ni] = __builtin_amdgcn_mfma_f32_16x16x32_f16(af[mi], bf[ni], acc[mi][ni], 0, 0, 0);
    }
#pragma unroll
    for (int mi = 0; mi < 4; ++mi) {
#pragma unroll
        for (int ni = 0; ni < 4; ++ni) {
#pragma unroll
            for (int j = 0; j < 4; ++j) {
                int r = bm + wr + mi * 16 + lhi * 4 + j;
                int c = bn + wc + ni * 16 + l16;
                float val = acc[mi][ni][j];
                if (EPI == 0) {
                    Cf[(size_t)r * N + c] = val;
                } else {
                    u16 hv = f2h(val);
                    int b = r >> 11, s = r & 2047;
                    if (c < 2048) {
                        int hh = c >> 7, d = c & 127;
                        qo[(((size_t)(b * 16 + hh)) * 2048 + s) * 128 + d] = hv;
                    } else if (c < 3072) {
                        int hh = (c - 2048) >> 7, d = c & 127;
                        ko[(((size_t)(b * 8 + hh)) * 2048 + s) * 128 + d] = hv;
                    } else {
                        int hh = (c - 3072) >> 7, d = c & 127;
                        vto[(((size_t)(b * 8 + hh)) * 128 + d) * 2048 + s] = hv;
                    }
                }
            }
        }
    }
}

// ---------------- RoPE (in-place on f16 (B,nh,S,128)) ----------------
__global__ void rope_kernel(u16* __restrict__ t, const float* __restrict__ cosv,
                            const float* __restrict__ sinv, int nheads) {
    int i = blockIdx.x * 256 + threadIdx.x;
    int total = 2 * nheads * 2048 * 64;
    if (i >= total) return;
    int d = i & 63;
    int s = (i >> 6) & 2047;
    int bh = i >> 17;
    int b = bh / nheads;
    size_t base = ((size_t)bh * 2048 + s) * 128;
    size_t cb = ((size_t)b * 2048 + s) * 128;
    float x1 = h2f(t[base + d]), x2 = h2f(t[base + d + 64]);
    float c1 = cosv[cb + d], s1 = sinv[cb + d];
    float c2 = cosv[cb + d + 64], s2 = sinv[cb + d + 64];
    t[base + d] = f2h(x1 * c1 - x2 * s1);
    t[base + d + 64] = f2h(x2 * c2 + x1 * s2);
}

// ---------------- Wdtv = Wdt (16x1024) @ Wv (1024x2048), f32 ----------------
__global__ void wdtv_kernel(const float* __restrict__ Wdt, const float* __restrict__ Wv,
                            float* __restrict__ out) {
    __shared__ float wdt_s[16 * 1024];
    int t = threadIdx.x;  // 64 threads
    for (int i = t; i < 16 * 1024; i += 64) wdt_s[i] = Wdt[i];
    __syncthreads();
    int c = blockIdx.x * 64 + t;
    float acc[16];
#pragma unroll
    for (int h = 0; h < 16; ++h) acc[h] = 0.f;
    for (int f = 0; f < 1024; ++f) {
        float wv = Wv[(size_t)f * 2048 + c];
#pragma unroll
        for (int h = 0; h < 16; ++h) acc[h] += wdt_s[h * 1024 + f] * wv;
    }
#pragma unroll
    for (int h = 0; h < 16; ++h) out[h * 2048 + c] = acc[h];
}

// ---------------- dt = x @ Wdtv^T ; dyn = exp(A*softplus(dt)), layout (B,H,S) f32 ----------------
__global__ void dt_dyn_kernel(const float* __restrict__ x, const float* __restrict__ Wdtv,
                              const float* __restrict__ Av, float* __restrict__ dyn) {
    __shared__ float xrow[2048];
    __shared__ float red[256];
    int bs = blockIdx.x;
    int t = threadIdx.x;
    for (int i = t; i < 2048; i += 256) xrow[i] = x[(size_t)bs * 2048 + i];
    __syncthreads();
    int h = t & 15, chunk = t >> 4;
    float p = 0.f;
    const float* wrow = Wdtv + h * 2048 + chunk * 128;
    const float* xr = xrow + chunk * 128;
    for (int f = 0; f < 128; ++f) p += xr[f] * wrow[f];
    red[t] = p;
    __syncthreads();
    if (t < 16) {
        float dt = 0.f;
        for (int c = 0; c < 16; ++c) dt += red[c * 16 + t];
        float sp = fmaxf(dt, 0.f) + log1pf(expf(-fabsf(dt)));
        int b = bs >> 11, s = bs & 2047;
        dyn[((size_t)(b * 16 + t)) * 2048 + s] = expf(Av[t] * sp);
    }
}

// ---------------- kth (1024th smallest of 2048) + mask values ----------------
__global__ void kth_mask_kernel(const float* __restrict__ dyn, float* __restrict__ mval) {
    __shared__ float sv[2048];
    int bh = blockIdx.x, t = threadIdx.x;  // 1024 threads
    const float* row = dyn + (size_t)bh * 2048;
    sv[t] = row[t];
    sv[t + 1024] = row[t + 1024];
    __syncthreads();
    for (int k = 2; k <= 2048; k <<= 1) {
        for (int j = k >> 1; j > 0; j >>= 1) {
#pragma unroll 1
            for (int base = 0; base < 2048; base += 1024) {
                int i = base + t;
                int ixj = i ^ j;
                if (ixj > i) {
                    float a = sv[i], b = sv[ixj];
                    bool up = ((i & k) == 0);
                    if ((a > b) == up) { sv[i] = b; sv[ixj] = a; }
                }
            }
            __syncthreads();
        }
    }
    float kth = sv[1023];
    float v0 = row[t];
    float v1 = row[t + 1024];
    mval[(size_t)bh * 2048 + t] = v0 < kth ? MINF : v0;
    mval[(size_t)bh * 2048 + t + 1024] = v1 < kth ? MINF : v1;
}

// ---------------- flash attention, causal + dynamic mask, GQA ----------------
// q: (B,16,S,128) f16; k: (B,8,S,128) f16; vt: (B,8,128,S) f16; mval: (B,16,S) f32
// out: attn_out (B,S,16*128) f16
// Block = 256 threads (4 waves). Block p covers 32-row tiles {p, 63-p} (balanced:
// total work/block ~constant). Waves 0,1 -> tile p; waves 2,3 -> tile 63-p.
// Grid (32 bh, 32 p) = 1024 blocks, all resident (4 blocks/CU).
__global__ __launch_bounds__(256) void attn_kernel(
    const u16* __restrict__ qb, const u16* __restrict__ kb, const u16* __restrict__ vtb,
    const float* __restrict__ mv, u16* __restrict__ ao) {
    int bh = blockIdx.x;
    int p = blockIdx.y;
    int b = bh >> 4, h = bh & 15, kvh = h >> 1;
    int wid = threadIdx.x >> 6, lane = threadIdx.x & 63;
    int l16 = lane & 15, lhi = lane >> 4;
    int qt = (wid < 2) ? p : (63 - p);
    int q0 = qt * 32 + (wid & 1) * 16;
    const u16* qbase = qb + (((size_t)bh * 2048) + q0) * 128;
    const u16* kbase = kb + ((size_t)(b * 8 + kvh) * 2048) * 128;
    const u16* vtbase = vtb + ((size_t)(b * 8 + kvh) * 128) * 2048;
    const float* mvb = mv + (size_t)bh * 2048;
    __shared__ alignas(16) u16 plds[4][16 * 64];
    u16* pw = plds[wid];
    f16x8 qf[4];
#pragma unroll
    for (int kc = 0; kc < 4; ++kc) qf[kc] = *(const f16x8*)&qbase[l16 * 128 + kc * 32 + lhi * 8];
    float m[4], lsum[4];
#pragma unroll
    for (int j = 0; j < 4; ++j) { m[j] = -INFINITY; lsum[j] = 0.f; }
    f32x4 accO[8] = {};
    for (int kt = 0; kt < 32; ++kt) {
        int kvb = kt * 64;
        if (kvb >= q0 + 16) {
            // past causal frontier for this wave: continue only for degenerate rows
            bool deg = (m[0] == MINF) | (m[1] == MINF) | (m[2] == MINF) | (m[3] == MINF);
            if (!__any(deg)) break;
        }
        f32x4 sc[4] = {};
        __builtin_amdgcn_s_setprio(1);
#pragma unroll
        for (int ni = 0; ni < 4; ++ni) {
            const u16* kr = &kbase[(size_t)(kvb + ni * 16 + l16) * 128 + lhi * 8];
#pragma unroll
            for (int kc = 0; kc < 4; ++kc) {
                f16x8 kf = *(const f16x8*)&kr[kc * 32];
                sc[ni] = __builtin_amdgcn_mfma_f32_16x16x32_f16(qf[kc], kf, sc[ni], 0, 0, 0);
            }
        }
        __builtin_amdgcn_s_setprio(0);
        float rmax[4] = {-INFINITY, -INFINITY, -INFINITY, -INFINITY};
#pragma unroll
        for (int ni = 0; ni < 4; ++ni) {
            int key = kvb + ni * 16 + l16;
            float mk = mvb[key];
#pragma unroll
            for (int j = 0; j < 4; ++j) {
                int qrow = q0 + lhi * 4 + j;
                // exact reference arithmetic: mask = dynmask + causalMIN (f32, may overflow to -inf),
                // then score = qk*scale + mask (MIN absorbs qk*scale).
                float sval = sc[ni][j] * SCALE + (mk + (key > qrow ? MINF : 0.f));
                sc[ni][j] = sval;
                rmax[j] = fmaxf(rmax[j], sval);
            }
        }
#pragma unroll
        for (int j = 0; j < 4; ++j) {
#pragma unroll
            for (int off = 1; off < 16; off <<= 1) rmax[j] = fmaxf(rmax[j], __shfl_xor(rmax[j], off));
        }
        float r[4], psum[4];
#pragma unroll
        for (int j = 0; j < 4; ++j) {
            float mn = fmaxf(m[j], rmax[j]);
            r[j] = __expf(m[j] - mn);
            m[j] = mn;
            psum[j] = 0.f;
        }
#pragma unroll
        for (int ni = 0; ni < 4; ++ni) {
#pragma unroll
            for (int j = 0; j < 4; ++j) {
                float pv = __expf(sc[ni][j] - m[j]);
                psum[j] += pv;
                pw[(lhi * 4 + j) * 64 + ni * 16 + l16] = f2h(pv);
            }
        }
#pragma unroll
        for (int j = 0; j < 4; ++j) {
#pragma unroll
            for (int off = 1; off < 16; off <<= 1) psum[j] += __shfl_xor(psum[j], off);
            lsum[j] = lsum[j] * r[j] + psum[j];
        }
#pragma unroll
        for (int db = 0; db < 8; ++db) {
#pragma unroll
            for (int j = 0; j < 4; ++j) accO[db][j] *= r[j];
        }
        __builtin_amdgcn_s_setprio(1);
#pragma unroll
        for (int kc2 = 0; kc2 < 2; ++kc2) {
            f16x8 pa = *(const f16x8*)&pw[l16 * 64 + kc2 * 32 + lhi * 8];
#pragma unroll
            for (int db = 0; db < 8; ++db) {
                f16x8 vf = *(const f16x8*)&vtbase[(size_t)(db * 16 + l16) * 2048 + kvb + kc2 * 32 + lhi * 8];
                accO[db] = __builtin_amdgcn_mfma_f32_16x16x32_f16(pa, vf, accO[db], 0, 0, 0);
            }
        }
        __builtin_amdgcn_s_setprio(0);
    }
#pragma unroll
    for (int db = 0; db < 8; ++db) {
#pragma unroll
        for (int j = 0; j < 4; ++j) {
            int qrow = q0 + lhi * 4 + j;
            int d = db * 16 + l16;
            float o = accO[db][j] / lsum[j];
            ao[((size_t)(b * 2048) + qrow) * 2048 + h * 128 + d] = f2h(o);
        }
    }
}

extern "C" void kernel_launch(void* const* d_in, const int* in_sizes, int n_in,
                              void* d_out, int out_size, void* d_ws, size_t ws_size,
                              hipStream_t stream) {
    const float* x = (const float*)d_in[0];
    const float* cosv = (const float*)d_in[1];
    const float* sinv = (const float*)d_in[2];
    // d_in[3] = attention_mask (deterministic causal MIN mask) -- synthesized in-kernel
    const float* Wq = (const float*)d_in[4];
    const float* Wk = (const float*)d_in[5];
    const float* Wv = (const float*)d_in[6];
    const float* Av = (const float*)d_in[7];
    const float* Wdt = (const float*)d_in[8];
    const float* Wo = (const float*)d_in[9];

    char* ws = (char*)d_ws;
    u16* qb = (u16*)(ws);                    // 16,777,216 B  (B,16,S,128) f16
    u16* kb = (u16*)(ws + 16777216);         //  8,388,608 B  (B,8,S,128) f16
    u16* vtb = (u16*)(ws + 25165824);        //  8,388,608 B  (B,8,128,S) f16
    float* dyn = (float*)(ws + 33554432);    //    262,144 B  (B,16,S) f32
    float* mval = (float*)(ws + 33816576);   //    262,144 B  (B,16,S) f32
    float* wdtv = (float*)(ws + 34078720);   //    131,072 B  (16,2048) f32
    u16* xbf = (u16*)(ws + 34209792);        // 16,777,216 B  x_f16, later attn_out
    u16* wbf = (u16*)(ws + 50987008);        // 16,777,216 B  Wqkv_f16, later Wo_f16

    // 1. conversions to f16 (8 elem/thread)
    convk8<<<8388608 / 2048, 256, 0, stream>>>(x, xbf, 8388608);
    convk8<<<4194304 / 2048, 256, 0, stream>>>(Wq, wbf, 4194304);
    convk8<<<2097152 / 2048, 256, 0, stream>>>(Wk, wbf + 4194304, 2097152);
    convk8<<<2097152 / 2048, 256, 0, stream>>>(Wv, wbf + 6291456, 2097152);

    // 2. fused QKV GEMM, scatter epilogue (q/k per-head layout, v transposed)
    dim3 g1(32, 32);
    gemm_bt<1><<<g1, 256, 0, stream>>>(xbf, wbf, nullptr, qb, kb, vtb, 4096, 2048);

    // 3. RoPE in-place on q and k
    rope_kernel<<<16384, 256, 0, stream>>>(qb, cosv, sinv, 16);
    rope_kernel<<<8192, 256, 0, stream>>>(kb, cosv, sinv, 8);

    // 4. dynamic mask: Wdtv = Wdt@Wv (f32), dt = x@Wdtv^T (f32, matches ref to ~1e-5), top-k
    wdtv_kernel<<<32, 64, 0, stream>>>(Wdt, Wv, wdtv);
    dt_dyn_kernel<<<4096, 256, 0, stream>>>(x, wdtv, Av, dyn);
    kth_mask_kernel<<<32, 1024, 0, stream>>>(dyn, mval);

    // 5. Wo -> f16 (reuses wbf; QKV GEMM is done by stream order)
    convk8<<<4194304 / 2048, 256, 0, stream>>>(Wo, wbf, 4194304);

    // 6. attention (writes attn_out into xbf); block p covers q-tiles {p, 63-p}
    dim3 g2(32, 32);
    attn_kernel<<<g2, 256, 0, stream>>>(qb, kb, vtb, mval, xbf);

    // 7. output projection -> f32 d_out
    dim3 g3(16, 32);
    gemm_bt<0><<<g3, 256, 0, stream>>>(xbf, wbf, (float*)d_out, nullptr, nullptr, nullptr, 2048, 2048);
}

// Round 6
// 602.089 us; speedup vs baseline: 1.2980x; 1.2980x over previous
//
#include <hip/hip_runtime.h>

typedef unsigned short u16;
typedef _Float16 f16x8 __attribute__((ext_vector_type(8)));
typedef float f32x4 __attribute__((ext_vector_type(4)));
typedef u16 u16x8 __attribute__((ext_vector_type(8)));

#define MINF (-0x1.fffffep+127f)
#define SCALE 0.08838834764831845f

__device__ __forceinline__ u16 f2h(float f) {
    _Float16 h = (_Float16)f;
    return __builtin_bit_cast(u16, h);
}
__device__ __forceinline__ float h2f(u16 u) {
    _Float16 h = __builtin_bit_cast(_Float16, u);
    return (float)h;
}

typedef const __attribute__((address_space(1))) void* gptr_t;
typedef __attribute__((address_space(3))) void* sptr_t;
#define GLDS16(g, l) __builtin_amdgcn_global_load_lds((gptr_t)(const void*)(g), (sptr_t)(void*)(l), 16, 0, 0)

// ---------------- f32 -> f16 conversion, 8 elem/thread (n must be divisible by 2048) ----------------
__global__ void convk8(const float* __restrict__ in, u16* __restrict__ out, int n) {
    int i = (blockIdx.x * 256 + threadIdx.x) * 8;
    if (i >= n) return;
    f32x4 a = *(const f32x4*)&in[i];
    f32x4 b = *(const f32x4*)&in[i + 4];
    u16x8 r;
#pragma unroll
    for (int j = 0; j < 4; ++j) { r[j] = f2h(a[j]); r[j + 4] = f2h(b[j]); }
    *(u16x8*)&out[i] = r;
}

// ---------------- GEMM C = A * Bw^T  (A: MxK row-major f16, Bw: NxK row-major f16) ----------------
// EPI=0: write f32 C (N param). EPI=1: QKV scatter epilogue (N=4096).
template <int EPI>
__global__ __launch_bounds__(256) void gemm_bt(
    const u16* __restrict__ A, const u16* __restrict__ Bw, float* __restrict__ Cf,
    u16* __restrict__ qo, u16* __restrict__ ko, u16* __restrict__ vto, int N, int K) {
    __shared__ alignas(16) u16 As[128 * 32];
    __shared__ alignas(16) u16 Bs[128 * 32];
    int tid = threadIdx.x;
    int wid = tid >> 6, lane = tid & 63;
    int l16 = lane & 15, lhi = lane >> 4;
    int bm = blockIdx.y * 128, bn = blockIdx.x * 128;
    int wr = (wid >> 1) * 64, wc = (wid & 1) * 64;
    int srow = lane >> 2, sseg = lane & 3;
    f32x4 acc[4][4] = {};
    for (int kt = 0; kt < K; kt += 32) {
        __syncthreads();
#pragma unroll
        for (int i = 0; i < 2; ++i) {
            const u16* ga = A + (size_t)(bm + i * 64 + wid * 16 + srow) * K + kt + sseg * 8;
            GLDS16(ga, &As[(i * 64 + wid * 16) * 32]);
            const u16* gb = Bw + (size_t)(bn + i * 64 + wid * 16 + srow) * K + kt + sseg * 8;
            GLDS16(gb, &Bs[(i * 64 + wid * 16) * 32]);
        }
        __syncthreads();
        f16x8 af[4], bf[4];
#pragma unroll
        for (int mi = 0; mi < 4; ++mi) af[mi] = *(const f16x8*)&As[(wr + mi * 16 + l16) * 32 + lhi * 8];
#pragma unroll
        for (int ni = 0; ni < 4; ++ni) bf[ni] = *(const f16x8*)&Bs[(wc + ni * 16 + l16) * 32 + lhi * 8];
#pragma unroll
        for (int mi = 0; mi < 4; ++mi)
#pragma unroll
            for (int ni = 0; ni < 4; ++ni)
                acc[mi][ni] = __builtin_amdgcn_mfma_f32_16x16x32_f16(af[mi], bf[ni], acc[mi][ni], 0, 0, 0);
    }
#pragma unroll
    for (int mi = 0; mi < 4; ++mi) {
#pragma unroll
        for (int ni = 0; ni < 4; ++ni) {
#pragma unroll
            for (int j = 0; j < 4; ++j) {
                int r = bm + wr + mi * 16 + lhi * 4 + j;
                int c = bn + wc + ni * 16 + l16;
                float val = acc[mi][ni][j];
                if (EPI == 0) {
                    Cf[(size_t)r * N + c] = val;
                } else {
                    u16 hv = f2h(val);
                    int b = r >> 11, s = r & 2047;
                    if (c < 2048) {
                        int hh = c >> 7, d = c & 127;
                        qo[(((size_t)(b * 16 + hh)) * 2048 + s) * 128 + d] = hv;
                    } else if (c < 3072) {
                        int hh = (c - 2048) >> 7, d = c & 127;
                        ko[(((size_t)(b * 8 + hh)) * 2048 + s) * 128 + d] = hv;
                    } else {
                        int hh = (c - 3072) >> 7, d = c & 127;
                        vto[(((size_t)(b * 8 + hh)) * 128 + d) * 2048 + s] = hv;
                    }
                }
            }
        }
    }
}

// ---------------- RoPE (in-place on f16 (B,nh,S,128)) ----------------
__global__ void rope_kernel(u16* __restrict__ t, const float* __restrict__ cosv,
                            const float* __restrict__ sinv, int nheads) {
    int i = blockIdx.x * 256 + threadIdx.x;
    int total = 2 * nheads * 2048 * 64;
    if (i >= total) return;
    int d = i & 63;
    int s = (i >> 6) & 2047;
    int bh = i >> 17;
    int b = bh / nheads;
    size_t base = ((size_t)bh * 2048 + s) * 128;
    size_t cb = ((size_t)b * 2048 + s) * 128;
    float x1 = h2f(t[base + d]), x2 = h2f(t[base + d + 64]);
    float c1 = cosv[cb + d], s1 = sinv[cb + d];
    float c2 = cosv[cb + d + 64], s2 = sinv[cb + d + 64];
    t[base + d] = f2h(x1 * c1 - x2 * s1);
    t[base + d + 64] = f2h(x2 * c2 + x1 * s2);
}

// ---------------- Wdtv = Wdt (16x1024) @ Wv (1024x2048), f32 ----------------
__global__ void wdtv_kernel(const float* __restrict__ Wdt, const float* __restrict__ Wv,
                            float* __restrict__ out) {
    __shared__ float wdt_s[16 * 1024];
    int t = threadIdx.x;  // 64 threads
    for (int i = t; i < 16 * 1024; i += 64) wdt_s[i] = Wdt[i];
    __syncthreads();
    int c = blockIdx.x * 64 + t;
    float acc[16];
#pragma unroll
    for (int h = 0; h < 16; ++h) acc[h] = 0.f;
    for (int f = 0; f < 1024; ++f) {
        float wv = Wv[(size_t)f * 2048 + c];
#pragma unroll
        for (int h = 0; h < 16; ++h) acc[h] += wdt_s[h * 1024 + f] * wv;
    }
#pragma unroll
    for (int h = 0; h < 16; ++h) out[h * 2048 + c] = acc[h];
}

// ---------------- dt = x @ Wdtv^T ; dyn = exp(A*softplus(dt)), layout (B,H,S) f32 ----------------
__global__ void dt_dyn_kernel(const float* __restrict__ x, const float* __restrict__ Wdtv,
                              const float* __restrict__ Av, float* __restrict__ dyn) {
    __shared__ float xrow[2048];
    __shared__ float red[256];
    int bs = blockIdx.x;
    int t = threadIdx.x;
    for (int i = t; i < 2048; i += 256) xrow[i] = x[(size_t)bs * 2048 + i];
    __syncthreads();
    int h = t & 15, chunk = t >> 4;
    float p = 0.f;
    const float* wrow = Wdtv + h * 2048 + chunk * 128;
    const float* xr = xrow + chunk * 128;
    for (int f = 0; f < 128; ++f) p += xr[f] * wrow[f];
    red[t] = p;
    __syncthreads();
    if (t < 16) {
        float dt = 0.f;
        for (int c = 0; c < 16; ++c) dt += red[c * 16 + t];
        float sp = fmaxf(dt, 0.f) + log1pf(expf(-fabsf(dt)));
        int b = bs >> 11, s = bs & 2047;
        dyn[((size_t)(b * 16 + t)) * 2048 + s] = expf(Av[t] * sp);
    }
}

// ---------------- kth (1024th smallest of 2048) + mask values ----------------
__global__ void kth_mask_kernel(const float* __restrict__ dyn, float* __restrict__ mval) {
    __shared__ float sv[2048];
    int bh = blockIdx.x, t = threadIdx.x;  // 1024 threads
    const float* row = dyn + (size_t)bh * 2048;
    sv[t] = row[t];
    sv[t + 1024] = row[t + 1024];
    __syncthreads();
    for (int k = 2; k <= 2048; k <<= 1) {
        for (int j = k >> 1; j > 0; j >>= 1) {
#pragma unroll 1
            for (int base = 0; base < 2048; base += 1024) {
                int i = base + t;
                int ixj = i ^ j;
                if (ixj > i) {
                    float a = sv[i], b = sv[ixj];
                    bool up = ((i & k) == 0);
                    if ((a > b) == up) { sv[i] = b; sv[ixj] = a; }
                }
            }
            __syncthreads();
        }
    }
    float kth = sv[1023];
    float v0 = row[t];
    float v1 = row[t + 1024];
    mval[(size_t)bh * 2048 + t] = v0 < kth ? MINF : v0;
    mval[(size_t)bh * 2048 + t + 1024] = v1 < kth ? MINF : v1;
}

// ---------------- flash attention, causal + dynamic mask, GQA ----------------
// q: (B,16,S,128) f16; k: (B,8,S,128) f16; vt: (B,8,128,S) f16; mval: (B,16,S) f32
// out: attn_out (B,S,16*128) f16
// Block = 256 threads (4 waves) = one 64-row q-tile. K/V tiles double-buffered in
// LDS via global_load_lds (2-phase: STAGE(t+1) || compute(t), one barrier/iter).
// LDS XOR-swizzle (chunk ^= row&7, 16B chunks) carried by pre-swizzled GLOBAL source
// (GLDS writes linearly) and applied on the ds_read side -> 2-way conflicts (free).
__global__ __launch_bounds__(256) void attn_kernel(
    const u16* __restrict__ qb, const u16* __restrict__ kb, const u16* __restrict__ vtb,
    const float* __restrict__ mv, u16* __restrict__ ao) {
    __shared__ alignas(16) u16 Kst[2][64 * 128];   // [buf][row 0..63][8-u16 chunk swizzled]
    __shared__ alignas(16) u16 Vst[2][128 * 64];   // [buf][d 0..127][chunk swizzled]
    __shared__ alignas(16) u16 plds[4][16 * 72];   // per-wave P, padded stride 72
    __shared__ int flags[4];
    int bh = blockIdx.x;
    int qt = 31 - blockIdx.y;  // longest-first (real queue: 1024 blocks > 512 resident)
    int b = bh >> 4, h = bh & 15, kvh = h >> 1;
    int wid = threadIdx.x >> 6, lane = threadIdx.x & 63;
    int l16 = lane & 15, lhi = lane >> 4;
    int q0 = qt * 64 + wid * 16;
    const u16* qbase = qb + (((size_t)bh * 2048) + q0) * 128;
    const u16* kbase = kb + ((size_t)(b * 8 + kvh) * 2048) * 128;
    const u16* vtbase = vtb + ((size_t)(b * 8 + kvh) * 128) * 2048;
    const float* mvb = mv + (size_t)bh * 2048;
    u16* pw = plds[wid];
    int rx = l16 & 7;  // row&7 for both K (ni*16+l16) and V (db*16+l16) reads

    // staging: 16 K-calls (4 rows/call) + 16 V-calls (8 rows/call), 4+4 per wave.
    // global source pre-swizzled so LDS chunk s of row r holds global chunk s^(r&7).
    auto STAGE = [&](int kt2, int bidx) {
        int kvb2 = kt2 * 64;
#pragma unroll
        for (int i = 0; i < 4; ++i) {
            int call = wid * 4 + i;
            int r = call * 4 + (lane >> 4);
            int gch = (lane & 15) ^ (r & 7);
            const u16* src = kbase + (size_t)(kvb2 + r) * 128 + gch * 8;
            GLDS16(src, &Kst[bidx][call * 512]);
        }
#pragma unroll
        for (int i = 0; i < 4; ++i) {
            int call = wid * 4 + i;
            int d = call * 8 + (lane >> 3);
            int gch = (lane & 7) ^ (d & 7);
            const u16* src = vtbase + (size_t)d * 2048 + kvb2 + gch * 8;
            GLDS16(src, &Vst[bidx][call * 512]);
        }
    };

    f16x8 qf[4];
#pragma unroll
    for (int kc = 0; kc < 4; ++kc) qf[kc] = *(const f16x8*)&qbase[l16 * 128 + kc * 32 + lhi * 8];
    float m[4], lsum[4];
#pragma unroll
    for (int j = 0; j < 4; ++j) { m[j] = -INFINITY; lsum[j] = 0.f; }
    f32x4 accO[8] = {};

    STAGE(0, 0);
    __syncthreads();

    for (int kt = 0; kt < 32; ++kt) {
        if (kt > qt) {
            // past the block's causal frontier: continue only while some row is degenerate
            if (!(flags[0] | flags[1] | flags[2] | flags[3])) break;
        }
        int buf = kt & 1;
        if (kt + 1 < 32) STAGE(kt + 1, buf ^ 1);  // async, lands before end-of-iter barrier
        int kvb = kt * 64;

        // QK^T from LDS (swizzled read)
        f32x4 sc[4] = {};
#pragma unroll
        for (int ni = 0; ni < 4; ++ni) {
            const u16* kr = &Kst[buf][(ni * 16 + l16) * 128];
#pragma unroll
            for (int kc = 0; kc < 4; ++kc) {
                int cc = (kc * 4 + lhi) ^ rx;
                f16x8 kf = *(const f16x8*)&kr[cc * 8];
                sc[ni] = __builtin_amdgcn_mfma_f32_16x16x32_f16(qf[kc], kf, sc[ni], 0, 0, 0);
            }
        }

        float rmax[4] = {-INFINITY, -INFINITY, -INFINITY, -INFINITY};
#pragma unroll
        for (int ni = 0; ni < 4; ++ni) {
            int key = kvb + ni * 16 + l16;
            float mk = mvb[key];
#pragma unroll
            for (int j = 0; j < 4; ++j) {
                int qrow = q0 + lhi * 4 + j;
                // exact reference arithmetic: mask = dynmask + causalMIN (f32, may -> -inf),
                // then score = qk*scale + mask (MIN absorbs qk*scale exactly).
                float sval = sc[ni][j] * SCALE + (mk + (key > qrow ? MINF : 0.f));
                sc[ni][j] = sval;
                rmax[j] = fmaxf(rmax[j], sval);
            }
        }
#pragma unroll
        for (int j = 0; j < 4; ++j) {
#pragma unroll
            for (int off = 1; off < 16; off <<= 1) rmax[j] = fmaxf(rmax[j], __shfl_xor(rmax[j], off));
        }
        float r[4], psum[4];
#pragma unroll
        for (int j = 0; j < 4; ++j) {
            float mn = fmaxf(m[j], rmax[j]);
            r[j] = __expf(m[j] - mn);
            m[j] = mn;
            psum[j] = 0.f;
        }
#pragma unroll
        for (int ni = 0; ni < 4; ++ni) {
#pragma unroll
            for (int j = 0; j < 4; ++j) {
                float pv = __expf(sc[ni][j] - m[j]);
                psum[j] += pv;
                pw[(lhi * 4 + j) * 72 + ni * 16 + l16] = f2h(pv);
            }
        }
#pragma unroll
        for (int j = 0; j < 4; ++j) {
#pragma unroll
            for (int off = 1; off < 16; off <<= 1) psum[j] += __shfl_xor(psum[j], off);
            lsum[j] = lsum[j] * r[j] + psum[j];
        }
#pragma unroll
        for (int db = 0; db < 8; ++db) {
#pragma unroll
            for (int j = 0; j < 4; ++j) accO[db][j] *= r[j];
        }

        // PV from LDS V (swizzled read)
#pragma unroll
        for (int kc2 = 0; kc2 < 2; ++kc2) {
            f16x8 pa = *(const f16x8*)&pw[l16 * 72 + kc2 * 32 + lhi * 8];
#pragma unroll
            for (int db = 0; db < 8; ++db) {
                int cc = (kc2 * 4 + lhi) ^ rx;
                f16x8 vf = *(const f16x8*)&Vst[buf][(db * 16 + l16) * 64 + cc * 8];
                accO[db] = __builtin_amdgcn_mfma_f32_16x16x32_f16(pa, vf, accO[db], 0, 0, 0);
            }
        }

        bool deg = (m[0] == MINF) | (m[1] == MINF) | (m[2] == MINF) | (m[3] == MINF);
        if (lane == 0) flags[wid] = __any(deg) ? 1 : 0;
        __syncthreads();  // drains vmcnt -> staged buf^1 ready; flags visible
    }

#pragma unroll
    for (int db = 0; db < 8; ++db) {
#pragma unroll
        for (int j = 0; j < 4; ++j) {
            int qrow = q0 + lhi * 4 + j;
            int d = db * 16 + l16;
            float o = accO[db][j] / lsum[j];
            ao[((size_t)(b * 2048) + qrow) * 2048 + h * 128 + d] = f2h(o);
        }
    }
}

extern "C" void kernel_launch(void* const* d_in, const int* in_sizes, int n_in,
                              void* d_out, int out_size, void* d_ws, size_t ws_size,
                              hipStream_t stream) {
    const float* x = (const float*)d_in[0];
    const float* cosv = (const float*)d_in[1];
    const float* sinv = (const float*)d_in[2];
    // d_in[3] = attention_mask (deterministic causal MIN mask) -- synthesized in-kernel
    const float* Wq = (const float*)d_in[4];
    const float* Wk = (const float*)d_in[5];
    const float* Wv = (const float*)d_in[6];
    const float* Av = (const float*)d_in[7];
    const float* Wdt = (const float*)d_in[8];
    const float* Wo = (const float*)d_in[9];

    char* ws = (char*)d_ws;
    u16* qb = (u16*)(ws);                    // 16,777,216 B  (B,16,S,128) f16
    u16* kb = (u16*)(ws + 16777216);         //  8,388,608 B  (B,8,S,128) f16
    u16* vtb = (u16*)(ws + 25165824);        //  8,388,608 B  (B,8,128,S) f16
    float* dyn = (float*)(ws + 33554432);    //    262,144 B  (B,16,S) f32
    float* mval = (float*)(ws + 33816576);   //    262,144 B  (B,16,S) f32
    float* wdtv = (float*)(ws + 34078720);   //    131,072 B  (16,2048) f32
    u16* xbf = (u16*)(ws + 34209792);        // 16,777,216 B  x_f16, later attn_out
    u16* wbf = (u16*)(ws + 50987008);        // 16,777,216 B  Wqkv_f16, later Wo_f16

    // 1. conversions to f16 (8 elem/thread)
    convk8<<<8388608 / 2048, 256, 0, stream>>>(x, xbf, 8388608);
    convk8<<<4194304 / 2048, 256, 0, stream>>>(Wq, wbf, 4194304);
    convk8<<<2097152 / 2048, 256, 0, stream>>>(Wk, wbf + 4194304, 2097152);
    convk8<<<2097152 / 2048, 256, 0, stream>>>(Wv, wbf + 6291456, 2097152);

    // 2. fused QKV GEMM, scatter epilogue (q/k per-head layout, v transposed)
    dim3 g1(32, 32);
    gemm_bt<1><<<g1, 256, 0, stream>>>(xbf, wbf, nullptr, qb, kb, vtb, 4096, 2048);

    // 3. RoPE in-place on q and k
    rope_kernel<<<16384, 256, 0, stream>>>(qb, cosv, sinv, 16);
    rope_kernel<<<8192, 256, 0, stream>>>(kb, cosv, sinv, 8);

    // 4. dynamic mask: Wdtv = Wdt@Wv (f32), dt = x@Wdtv^T (f32, matches ref to ~1e-5), top-k
    wdtv_kernel<<<32, 64, 0, stream>>>(Wdt, Wv, wdtv);
    dt_dyn_kernel<<<4096, 256, 0, stream>>>(x, wdtv, Av, dyn);
    kth_mask_kernel<<<32, 1024, 0, stream>>>(dyn, mval);

    // 5. Wo -> f16 (reuses wbf; QKV GEMM is done by stream order)
    convk8<<<4194304 / 2048, 256, 0, stream>>>(Wo, wbf, 4194304);

    // 6. attention (writes attn_out into xbf)
    dim3 g2(32, 32);
    attn_kernel<<<g2, 256, 0, stream>>>(qb, kb, vtb, mval, xbf);

    // 7. output projection -> f32 d_out
    dim3 g3(16, 32);
    gemm_bt<0><<<g3, 256, 0, stream>>>(xbf, wbf, (float*)d_out, nullptr, nullptr, nullptr, 2048, 2048);
}

// Round 9
// 570.294 us; speedup vs baseline: 1.3704x; 1.0558x over previous
//
#include <hip/hip_runtime.h>

typedef unsigned short u16;
typedef _Float16 f16x8 __attribute__((ext_vector_type(8)));
typedef float f32x4 __attribute__((ext_vector_type(4)));
typedef u16 u16x8 __attribute__((ext_vector_type(8)));

#define MINF (-0x1.fffffep+127f)
#define SCALE 0.08838834764831845f

__device__ __forceinline__ u16 f2h(float f) {
    _Float16 h = (_Float16)f;
    return __builtin_bit_cast(u16, h);
}
__device__ __forceinline__ float h2f(u16 u) {
    _Float16 h = __builtin_bit_cast(_Float16, u);
    return (float)h;
}

typedef const __attribute__((address_space(1))) void* gptr_t;
typedef __attribute__((address_space(3))) void* sptr_t;
#define GLDS16(g, l) __builtin_amdgcn_global_load_lds((gptr_t)(const void*)(g), (sptr_t)(void*)(l), 16, 0, 0)

// ---------------- f32 -> f16 conversion, 8 elem/thread (n must be divisible by 2048) ----------------
__global__ void convk8(const float* __restrict__ in, u16* __restrict__ out, int n) {
    int i = (blockIdx.x * 256 + threadIdx.x) * 8;
    if (i >= n) return;
    f32x4 a = *(const f32x4*)&in[i];
    f32x4 b = *(const f32x4*)&in[i + 4];
    u16x8 r;
#pragma unroll
    for (int j = 0; j < 4; ++j) { r[j] = f2h(a[j]); r[j + 4] = f2h(b[j]); }
    *(u16x8*)&out[i] = r;
}

// ---------------- QKV GEMM, 256x256 tile, BK=64, 8 waves, counted-vmcnt prefetch (T3/T4) -------
// C = A (4096x2048 f16) * Bw^T (4096x2048 f16), scatter epilogue to q/k/vt.
// LDS: [2 buf][2 half][128 rows][64 cols] for A and B = 128 KB. XOR swizzle chunk^=row&7,
// carried by pre-swizzled global source (GLDS writes linearly), applied on ds_read.
// Sync per K-tile: barrier (reads drained) -> STAGE(t+2) -> vmcnt(8) [counted: t+1 done,
// t+2 in flight] -> barrier. Never vmcnt(0) in steady state.
__global__ __launch_bounds__(512, 1) void gemm8_qkv(
    const u16* __restrict__ A, const u16* __restrict__ Bw,
    u16* __restrict__ qo, u16* __restrict__ ko, u16* __restrict__ vto) {
    __shared__ alignas(16) u16 AS[2][2][128 * 64];
    __shared__ alignas(16) u16 BS[2][2][128 * 64];
    const int K = 2048, NT = 32;
    int tid = threadIdx.x;
    int wid = tid >> 6, lane = tid & 63;
    int l16 = lane & 15, lhi = lane >> 4;
    int wm = wid >> 2, wn = wid & 3;
    int bm = blockIdx.y * 256, bn = blockIdx.x * 256;
    int srow = lane >> 3;                   // 0..7
    int schunk = (lane & 7) ^ srow;         // pre-swizzled source chunk (row&7 == srow)
    f32x4 acc[8][4] = {};

    // one K-tile stage = 8 GLDS/wave (2 calls x 4 panels), 16 KB x 4 panels total
    auto STAGE = [&](int t, int buf) {
        int kt = t * 64;
#pragma unroll
        for (int i = 0; i < 2; ++i) {
            int c = wid * 2 + i;            // 0..15
            int row = c * 8 + srow;         // 0..127
            const u16* sa0 = A + (size_t)(bm + row) * K + kt + schunk * 8;
            GLDS16(sa0, &AS[buf][0][c * 512]);
            const u16* sa1 = A + (size_t)(bm + 128 + row) * K + kt + schunk * 8;
            GLDS16(sa1, &AS[buf][1][c * 512]);
            const u16* sb0 = Bw + (size_t)(bn + row) * K + kt + schunk * 8;
            GLDS16(sb0, &BS[buf][0][c * 512]);
            const u16* sb1 = Bw + (size_t)(bn + 128 + row) * K + kt + schunk * 8;
            GLDS16(sb1, &BS[buf][1][c * 512]);
        }
    };

    auto COMPUTE = [&](int buf) {
#pragma unroll
        for (int kk = 0; kk < 2; ++kk) {
            f16x8 af[8], bf[4];
#pragma unroll
            for (int ni = 0; ni < 4; ++ni) {
                int rb = wn * 64 + ni * 16 + l16;     // 0..255
                int half = rb >> 7, rh = rb & 127;
                int c2 = (kk * 4 + lhi) ^ (rh & 7);
                bf[ni] = *(const f16x8*)&BS[buf][half][rh * 64 + c2 * 8];
            }
#pragma unroll
            for (int mi = 0; mi < 8; ++mi) {
                int rh = mi * 16 + l16;
                int c2 = (kk * 4 + lhi) ^ (rh & 7);
                af[mi] = *(const f16x8*)&AS[buf][wm][rh * 64 + c2 * 8];
            }
            __builtin_amdgcn_s_setprio(1);
#pragma unroll
            for (int mi = 0; mi < 8; ++mi)
#pragma unroll
                for (int ni = 0; ni < 4; ++ni)
                    acc[mi][ni] = __builtin_amdgcn_mfma_f32_16x16x32_f16(af[mi], bf[ni], acc[mi][ni], 0, 0, 0);
            __builtin_amdgcn_s_setprio(0);
        }
    };

    STAGE(0, 0);
    STAGE(1, 1);
    asm volatile("s_waitcnt vmcnt(8)" ::: "memory");   // tile0 resident (tile1 in flight)
    __builtin_amdgcn_sched_barrier(0);
    __builtin_amdgcn_s_barrier();

    for (int t = 0; t < NT; ++t) {
        int buf = t & 1;
        COMPUTE(buf);
        __builtin_amdgcn_s_barrier();                  // all waves done reading buf
        if (t + 2 < NT) {
            STAGE(t + 2, buf);                         // overwrite drained buf
            asm volatile("s_waitcnt vmcnt(8)" ::: "memory");  // t+1 resident, t+2 in flight
        } else {
            asm volatile("s_waitcnt vmcnt(0)" ::: "memory");  // tail drain
        }
        __builtin_amdgcn_sched_barrier(0);
        __builtin_amdgcn_s_barrier();                  // buf^1 valid for everyone
    }

    // scatter epilogue: r/c -> q (B,16,S,128), k (B,8,S,128), vt (B,8,128,S)
#pragma unroll
    for (int mi = 0; mi < 8; ++mi) {
#pragma unroll
        for (int ni = 0; ni < 4; ++ni) {
#pragma unroll
            for (int j = 0; j < 4; ++j) {
                int r = bm + wm * 128 + mi * 16 + lhi * 4 + j;
                int c = bn + wn * 64 + ni * 16 + l16;
                u16 hv = f2h(acc[mi][ni][j]);
                int b = r >> 11, s = r & 2047;
                if (c < 2048) {
                    int hh = c >> 7, d = c & 127;
                    qo[(((size_t)(b * 16 + hh)) * 2048 + s) * 128 + d] = hv;
                } else if (c < 3072) {
                    int hh = (c - 2048) >> 7, d = c & 127;
                    ko[(((size_t)(b * 8 + hh)) * 2048 + s) * 128 + d] = hv;
                } else {
                    int hh = (c - 3072) >> 7, d = c & 127;
                    vto[(((size_t)(b * 8 + hh)) * 128 + d) * 2048 + s] = hv;
                }
            }
        }
    }
}

// ---------------- GEMM C = A * Bw^T (m97 structure) -- used for output projection ----------------
__global__ __launch_bounds__(256) void gemm_bt0(
    const u16* __restrict__ A, const u16* __restrict__ Bw, float* __restrict__ Cf, int N, int K) {
    __shared__ alignas(16) u16 As[128 * 32];
    __shared__ alignas(16) u16 Bs[128 * 32];
    int tid = threadIdx.x;
    int wid = tid >> 6, lane = tid & 63;
    int l16 = lane & 15, lhi = lane >> 4;
    int bm = blockIdx.y * 128, bn = blockIdx.x * 128;
    int wr = (wid >> 1) * 64, wc = (wid & 1) * 64;
    int srow = lane >> 2, sseg = lane & 3;
    f32x4 acc[4][4] = {};
    for (int kt = 0; kt < K; kt += 32) {
        __syncthreads();
#pragma unroll
        for (int i = 0; i < 2; ++i) {
            const u16* ga = A + (size_t)(bm + i * 64 + wid * 16 + srow) * K + kt + sseg * 8;
            GLDS16(ga, &As[(i * 64 + wid * 16) * 32]);
            const u16* gb = Bw + (size_t)(bn + i * 64 + wid * 16 + srow) * K + kt + sseg * 8;
            GLDS16(gb, &Bs[(i * 64 + wid * 16) * 32]);
        }
        __syncthreads();
        f16x8 af[4], bf[4];
#pragma unroll
        for (int mi = 0; mi < 4; ++mi) af[mi] = *(const f16x8*)&As[(wr + mi * 16 + l16) * 32 + lhi * 8];
#pragma unroll
        for (int ni = 0; ni < 4; ++ni) bf[ni] = *(const f16x8*)&Bs[(wc + ni * 16 + l16) * 32 + lhi * 8];
#pragma unroll
        for (int mi = 0; mi < 4; ++mi)
#pragma unroll
            for (int ni = 0; ni < 4; ++ni)
                acc[mi][ni] = __builtin_amdgcn_mfma_f32_16x16x32_f16(af[mi], bf[ni], acc[mi][ni], 0, 0, 0);
    }
#pragma unroll
    for (int mi = 0; mi < 4; ++mi)
#pragma unroll
        for (int ni = 0; ni < 4; ++ni)
#pragma unroll
            for (int j = 0; j < 4; ++j) {
                int r = bm + wr + mi * 16 + lhi * 4 + j;
                int c = bn + wc + ni * 16 + l16;
                Cf[(size_t)r * N + c] = acc[mi][ni][j];
            }
}

// ---------------- RoPE (in-place on f16 (B,nh,S,128)) ----------------
__global__ void rope_kernel(u16* __restrict__ t, const float* __restrict__ cosv,
                            const float* __restrict__ sinv, int nheads) {
    int i = blockIdx.x * 256 + threadIdx.x;
    int total = 2 * nheads * 2048 * 64;
    if (i >= total) return;
    int d = i & 63;
    int s = (i >> 6) & 2047;
    int bh = i >> 17;
    int b = bh / nheads;
    size_t base = ((size_t)bh * 2048 + s) * 128;
    size_t cb = ((size_t)b * 2048 + s) * 128;
    float x1 = h2f(t[base + d]), x2 = h2f(t[base + d + 64]);
    float c1 = cosv[cb + d], s1 = sinv[cb + d];
    float c2 = cosv[cb + d + 64], s2 = sinv[cb + d + 64];
    t[base + d] = f2h(x1 * c1 - x2 * s1);
    t[base + d + 64] = f2h(x2 * c2 + x1 * s2);
}

// ---------------- Wdtv = Wdt (16x1024) @ Wv (1024x2048), f32 ----------------
__global__ void wdtv_kernel(const float* __restrict__ Wdt, const float* __restrict__ Wv,
                            float* __restrict__ out) {
    __shared__ float wdt_s[16 * 1024];
    int t = threadIdx.x;  // 64 threads
    for (int i = t; i < 16 * 1024; i += 64) wdt_s[i] = Wdt[i];
    __syncthreads();
    int c = blockIdx.x * 64 + t;
    float acc[16];
#pragma unroll
    for (int h = 0; h < 16; ++h) acc[h] = 0.f;
    for (int f = 0; f < 1024; ++f) {
        float wv = Wv[(size_t)f * 2048 + c];
#pragma unroll
        for (int h = 0; h < 16; ++h) acc[h] += wdt_s[h * 1024 + f] * wv;
    }
#pragma unroll
    for (int h = 0; h < 16; ++h) out[h * 2048 + c] = acc[h];
}

// ---------------- dt = x @ Wdtv^T ; dyn = exp(A*softplus(dt)), layout (B,H,S) f32 ----------------
__global__ void dt_dyn_kernel(const float* __restrict__ x, const float* __restrict__ Wdtv,
                              const float* __restrict__ Av, float* __restrict__ dyn) {
    __shared__ float xrow[2048];
    __shared__ float red[256];
    int bs = blockIdx.x;
    int t = threadIdx.x;
    for (int i = t; i < 2048; i += 256) xrow[i] = x[(size_t)bs * 2048 + i];
    __syncthreads();
    int h = t & 15, chunk = t >> 4;
    float p = 0.f;
    const float* wrow = Wdtv + h * 2048 + chunk * 128;
    const float* xr = xrow + chunk * 128;
    for (int f = 0; f < 128; ++f) p += xr[f] * wrow[f];
    red[t] = p;
    __syncthreads();
    if (t < 16) {
        float dt = 0.f;
        for (int c = 0; c < 16; ++c) dt += red[c * 16 + t];
        float sp = fmaxf(dt, 0.f) + log1pf(expf(-fabsf(dt)));
        int b = bs >> 11, s = bs & 2047;
        dyn[((size_t)(b * 16 + t)) * 2048 + s] = expf(Av[t] * sp);
    }
}

// ---------------- kth (1024th smallest of 2048) + mask values ----------------
__global__ void kth_mask_kernel(const float* __restrict__ dyn, float* __restrict__ mval) {
    __shared__ float sv[2048];
    int bh = blockIdx.x, t = threadIdx.x;  // 1024 threads
    const float* row = dyn + (size_t)bh * 2048;
    sv[t] = row[t];
    sv[t + 1024] = row[t + 1024];
    __syncthreads();
    for (int k = 2; k <= 2048; k <<= 1) {
        for (int j = k >> 1; j > 0; j >>= 1) {
#pragma unroll 1
            for (int base = 0; base < 2048; base += 1024) {
                int i = base + t;
                int ixj = i ^ j;
                if (ixj > i) {
                    float a = sv[i], b = sv[ixj];
                    bool up = ((i & k) == 0);
                    if ((a > b) == up) { sv[i] = b; sv[ixj] = a; }
                }
            }
            __syncthreads();
        }
    }
    float kth = sv[1023];
    float v0 = row[t];
    float v1 = row[t + 1024];
    mval[(size_t)bh * 2048 + t] = v0 < kth ? MINF : v0;
    mval[(size_t)bh * 2048 + t + 1024] = v1 < kth ? MINF : v1;
}

// ---------------- flash attention, causal + dynamic mask, GQA (unchanged from R5) ----------------
__global__ __launch_bounds__(256) void attn_kernel(
    const u16* __restrict__ qb, const u16* __restrict__ kb, const u16* __restrict__ vtb,
    const float* __restrict__ mv, u16* __restrict__ ao) {
    __shared__ alignas(16) u16 Kst[2][64 * 128];
    __shared__ alignas(16) u16 Vst[2][128 * 64];
    __shared__ alignas(16) u16 plds[4][16 * 72];
    __shared__ int flags[4];
    int bh = blockIdx.x;
    int qt = 31 - blockIdx.y;
    int b = bh >> 4, h = bh & 15, kvh = h >> 1;
    int wid = threadIdx.x >> 6, lane = threadIdx.x & 63;
    int l16 = lane & 15, lhi = lane >> 4;
    int q0 = qt * 64 + wid * 16;
    const u16* qbase = qb + (((size_t)bh * 2048) + q0) * 128;
    const u16* kbase = kb + ((size_t)(b * 8 + kvh) * 2048) * 128;
    const u16* vtbase = vtb + ((size_t)(b * 8 + kvh) * 128) * 2048;
    const float* mvb = mv + (size_t)bh * 2048;
    u16* pw = plds[wid];
    int rx = l16 & 7;

    auto STAGE = [&](int kt2, int bidx) {
        int kvb2 = kt2 * 64;
#pragma unroll
        for (int i = 0; i < 4; ++i) {
            int call = wid * 4 + i;
            int r = call * 4 + (lane >> 4);
            int gch = (lane & 15) ^ (r & 7);
            const u16* src = kbase + (size_t)(kvb2 + r) * 128 + gch * 8;
            GLDS16(src, &Kst[bidx][call * 512]);
        }
#pragma unroll
        for (int i = 0; i < 4; ++i) {
            int call = wid * 4 + i;
            int d = call * 8 + (lane >> 3);
            int gch = (lane & 7) ^ (d & 7);
            const u16* src = vtbase + (size_t)d * 2048 + kvb2 + gch * 8;
            GLDS16(src, &Vst[bidx][call * 512]);
        }
    };

    f16x8 qf[4];
#pragma unroll
    for (int kc = 0; kc < 4; ++kc) qf[kc] = *(const f16x8*)&qbase[l16 * 128 + kc * 32 + lhi * 8];
    float m[4], lsum[4];
#pragma unroll
    for (int j = 0; j < 4; ++j) { m[j] = -INFINITY; lsum[j] = 0.f; }
    f32x4 accO[8] = {};

    STAGE(0, 0);
    __syncthreads();

    for (int kt = 0; kt < 32; ++kt) {
        if (kt > qt) {
            if (!(flags[0] | flags[1] | flags[2] | flags[3])) break;
        }
        int buf = kt & 1;
        if (kt + 1 < 32) STAGE(kt + 1, buf ^ 1);
        int kvb = kt * 64;

        f32x4 sc[4] = {};
#pragma unroll
        for (int ni = 0; ni < 4; ++ni) {
            const u16* kr = &Kst[buf][(ni * 16 + l16) * 128];
#pragma unroll
            for (int kc = 0; kc < 4; ++kc) {
                int cc = (kc * 4 + lhi) ^ rx;
                f16x8 kf = *(const f16x8*)&kr[cc * 8];
                sc[ni] = __builtin_amdgcn_mfma_f32_16x16x32_f16(qf[kc], kf, sc[ni], 0, 0, 0);
            }
        }

        float rmax[4] = {-INFINITY, -INFINITY, -INFINITY, -INFINITY};
#pragma unroll
        for (int ni = 0; ni < 4; ++ni) {
            int key = kvb + ni * 16 + l16;
            float mk = mvb[key];
#pragma unroll
            for (int j = 0; j < 4; ++j) {
                int qrow = q0 + lhi * 4 + j;
                float sval = sc[ni][j] * SCALE + (mk + (key > qrow ? MINF : 0.f));
                sc[ni][j] = sval;
                rmax[j] = fmaxf(rmax[j], sval);
            }
        }
#pragma unroll
        for (int j = 0; j < 4; ++j) {
#pragma unroll
            for (int off = 1; off < 16; off <<= 1) rmax[j] = fmaxf(rmax[j], __shfl_xor(rmax[j], off));
        }
        float r[4], psum[4];
#pragma unroll
        for (int j = 0; j < 4; ++j) {
            float mn = fmaxf(m[j], rmax[j]);
            r[j] = __expf(m[j] - mn);
            m[j] = mn;
            psum[j] = 0.f;
        }
#pragma unroll
        for (int ni = 0; ni < 4; ++ni) {
#pragma unroll
            for (int j = 0; j < 4; ++j) {
                float pv = __expf(sc[ni][j] - m[j]);
                psum[j] += pv;
                pw[(lhi * 4 + j) * 72 + ni * 16 + l16] = f2h(pv);
            }
        }
#pragma unroll
        for (int j = 0; j < 4; ++j) {
#pragma unroll
            for (int off = 1; off < 16; off <<= 1) psum[j] += __shfl_xor(psum[j], off);
            lsum[j] = lsum[j] * r[j] + psum[j];
        }
#pragma unroll
        for (int db = 0; db < 8; ++db) {
#pragma unroll
            for (int j = 0; j < 4; ++j) accO[db][j] *= r[j];
        }
#pragma unroll
        for (int kc2 = 0; kc2 < 2; ++kc2) {
            f16x8 pa = *(const f16x8*)&pw[l16 * 72 + kc2 * 32 + lhi * 8];
#pragma unroll
            for (int db = 0; db < 8; ++db) {
                int cc = (kc2 * 4 + lhi) ^ rx;
                f16x8 vf = *(const f16x8*)&Vst[buf][(db * 16 + l16) * 64 + cc * 8];
                accO[db] = __builtin_amdgcn_mfma_f32_16x16x32_f16(pa, vf, accO[db], 0, 0, 0);
            }
        }

        bool deg = (m[0] == MINF) | (m[1] == MINF) | (m[2] == MINF) | (m[3] == MINF);
        if (lane == 0) flags[wid] = __any(deg) ? 1 : 0;
        __syncthreads();
    }

#pragma unroll
    for (int db = 0; db < 8; ++db) {
#pragma unroll
        for (int j = 0; j < 4; ++j) {
            int qrow = q0 + lhi * 4 + j;
            int d = db * 16 + l16;
            float o = accO[db][j] / lsum[j];
            ao[((size_t)(b * 2048) + qrow) * 2048 + h * 128 + d] = f2h(o);
        }
    }
}

extern "C" void kernel_launch(void* const* d_in, const int* in_sizes, int n_in,
                              void* d_out, int out_size, void* d_ws, size_t ws_size,
                              hipStream_t stream) {
    const float* x = (const float*)d_in[0];
    const float* cosv = (const float*)d_in[1];
    const float* sinv = (const float*)d_in[2];
    const float* Wq = (const float*)d_in[4];
    const float* Wk = (const float*)d_in[5];
    const float* Wv = (const float*)d_in[6];
    const float* Av = (const float*)d_in[7];
    const float* Wdt = (const float*)d_in[8];
    const float* Wo = (const float*)d_in[9];

    char* ws = (char*)d_ws;
    u16* qb = (u16*)(ws);
    u16* kb = (u16*)(ws + 16777216);
    u16* vtb = (u16*)(ws + 25165824);
    float* dyn = (float*)(ws + 33554432);
    float* mval = (float*)(ws + 33816576);
    float* wdtv = (float*)(ws + 34078720);
    u16* xbf = (u16*)(ws + 34209792);
    u16* wbf = (u16*)(ws + 50987008);

    // 1. conversions to f16
    convk8<<<8388608 / 2048, 256, 0, stream>>>(x, xbf, 8388608);
    convk8<<<4194304 / 2048, 256, 0, stream>>>(Wq, wbf, 4194304);
    convk8<<<2097152 / 2048, 256, 0, stream>>>(Wk, wbf + 4194304, 2097152);
    convk8<<<2097152 / 2048, 256, 0, stream>>>(Wv, wbf + 6291456, 2097152);

    // 2. fused QKV GEMM (256^2 tile, counted-vmcnt prefetch), scatter epilogue
    dim3 g1(16, 16);
    gemm8_qkv<<<g1, 512, 0, stream>>>(xbf, wbf, qb, kb, vtb);

    // 3. RoPE in-place on q and k
    rope_kernel<<<16384, 256, 0, stream>>>(qb, cosv, sinv, 16);
    rope_kernel<<<8192, 256, 0, stream>>>(kb, cosv, sinv, 8);

    // 4. dynamic mask path (f32-exact dt)
    wdtv_kernel<<<32, 64, 0, stream>>>(Wdt, Wv, wdtv);
    dt_dyn_kernel<<<4096, 256, 0, stream>>>(x, wdtv, Av, dyn);
    kth_mask_kernel<<<32, 1024, 0, stream>>>(dyn, mval);

    // 5. Wo -> f16
    convk8<<<4194304 / 2048, 256, 0, stream>>>(Wo, wbf, 4194304);

    // 6. attention
    dim3 g2(32, 32);
    attn_kernel<<<g2, 256, 0, stream>>>(qb, kb, vtb, mval, xbf);

    // 7. output projection -> f32 d_out
    dim3 g3(16, 32);
    gemm_bt0<<<g3, 256, 0, stream>>>(xbf, wbf, (float*)d_out, 2048, 2048);
}

// Round 10
// 463.058 us; speedup vs baseline: 1.6877x; 1.2316x over previous
//
#include <hip/hip_runtime.h>

typedef unsigned short u16;
typedef _Float16 f16x8 __attribute__((ext_vector_type(8)));
typedef float f32x4 __attribute__((ext_vector_type(4)));
typedef u16 u16x8 __attribute__((ext_vector_type(8)));

#define MINF (-0x1.fffffep+127f)
#define SCALE 0.08838834764831845f

__device__ __forceinline__ u16 f2h(float f) {
    _Float16 h = (_Float16)f;
    return __builtin_bit_cast(u16, h);
}
__device__ __forceinline__ float h2f(u16 u) {
    _Float16 h = __builtin_bit_cast(_Float16, u);
    return (float)h;
}

typedef const __attribute__((address_space(1))) void* gptr_t;
typedef __attribute__((address_space(3))) void* sptr_t;
#define GLDS16(g, l) __builtin_amdgcn_global_load_lds((gptr_t)(const void*)(g), (sptr_t)(void*)(l), 16, 0, 0)

// ---------------- f32 -> f16 conversion, 8 elem/thread (n must be divisible by 2048) ----------------
__global__ void convk8(const float* __restrict__ in, u16* __restrict__ out, int n) {
    int i = (blockIdx.x * 256 + threadIdx.x) * 8;
    if (i >= n) return;
    f32x4 a = *(const f32x4*)&in[i];
    f32x4 b = *(const f32x4*)&in[i + 4];
    u16x8 r;
#pragma unroll
    for (int j = 0; j < 4; ++j) { r[j] = f2h(a[j]); r[j + 4] = f2h(b[j]); }
    *(u16x8*)&out[i] = r;
}

// ---------------- QKV GEMM, 256x256 tile, BK=64, 8 waves, counted-vmcnt prefetch (T3/T4) -------
__global__ __launch_bounds__(512, 1) void gemm8_qkv(
    const u16* __restrict__ A, const u16* __restrict__ Bw,
    u16* __restrict__ qo, u16* __restrict__ ko, u16* __restrict__ vto) {
    __shared__ alignas(16) u16 AS[2][2][128 * 64];
    __shared__ alignas(16) u16 BS[2][2][128 * 64];
    const int K = 2048, NT = 32;
    int tid = threadIdx.x;
    int wid = tid >> 6, lane = tid & 63;
    int l16 = lane & 15, lhi = lane >> 4;
    int wm = wid >> 2, wn = wid & 3;
    int bm = blockIdx.y * 256, bn = blockIdx.x * 256;
    int srow = lane >> 3;                   // 0..7
    int schunk = (lane & 7) ^ srow;         // pre-swizzled source chunk (row&7 == srow)
    f32x4 acc[8][4] = {};

    auto STAGE = [&](int t, int buf) {
        int kt = t * 64;
#pragma unroll
        for (int i = 0; i < 2; ++i) {
            int c = wid * 2 + i;            // 0..15
            int row = c * 8 + srow;         // 0..127
            const u16* sa0 = A + (size_t)(bm + row) * K + kt + schunk * 8;
            GLDS16(sa0, &AS[buf][0][c * 512]);
            const u16* sa1 = A + (size_t)(bm + 128 + row) * K + kt + schunk * 8;
            GLDS16(sa1, &AS[buf][1][c * 512]);
            const u16* sb0 = Bw + (size_t)(bn + row) * K + kt + schunk * 8;
            GLDS16(sb0, &BS[buf][0][c * 512]);
            const u16* sb1 = Bw + (size_t)(bn + 128 + row) * K + kt + schunk * 8;
            GLDS16(sb1, &BS[buf][1][c * 512]);
        }
    };

    auto COMPUTE = [&](int buf) {
#pragma unroll
        for (int kk = 0; kk < 2; ++kk) {
            f16x8 af[8], bf[4];
#pragma unroll
            for (int ni = 0; ni < 4; ++ni) {
                int rb = wn * 64 + ni * 16 + l16;     // 0..255
                int half = rb >> 7, rh = rb & 127;
                int c2 = (kk * 4 + lhi) ^ (rh & 7);
                bf[ni] = *(const f16x8*)&BS[buf][half][rh * 64 + c2 * 8];
            }
#pragma unroll
            for (int mi = 0; mi < 8; ++mi) {
                int rh = mi * 16 + l16;
                int c2 = (kk * 4 + lhi) ^ (rh & 7);
                af[mi] = *(const f16x8*)&AS[buf][wm][rh * 64 + c2 * 8];
            }
            __builtin_amdgcn_s_setprio(1);
#pragma unroll
            for (int mi = 0; mi < 8; ++mi)
#pragma unroll
                for (int ni = 0; ni < 4; ++ni)
                    acc[mi][ni] = __builtin_amdgcn_mfma_f32_16x16x32_f16(af[mi], bf[ni], acc[mi][ni], 0, 0, 0);
            __builtin_amdgcn_s_setprio(0);
        }
    };

    STAGE(0, 0);
    STAGE(1, 1);
    asm volatile("s_waitcnt vmcnt(8)" ::: "memory");
    __builtin_amdgcn_sched_barrier(0);
    __builtin_amdgcn_s_barrier();

    for (int t = 0; t < NT; ++t) {
        int buf = t & 1;
        COMPUTE(buf);
        __builtin_amdgcn_s_barrier();
        if (t + 2 < NT) {
            STAGE(t + 2, buf);
            asm volatile("s_waitcnt vmcnt(8)" ::: "memory");
        } else {
            asm volatile("s_waitcnt vmcnt(0)" ::: "memory");
        }
        __builtin_amdgcn_sched_barrier(0);
        __builtin_amdgcn_s_barrier();
    }

#pragma unroll
    for (int mi = 0; mi < 8; ++mi) {
#pragma unroll
        for (int ni = 0; ni < 4; ++ni) {
#pragma unroll
            for (int j = 0; j < 4; ++j) {
                int r = bm + wm * 128 + mi * 16 + lhi * 4 + j;
                int c = bn + wn * 64 + ni * 16 + l16;
                u16 hv = f2h(acc[mi][ni][j]);
                int b = r >> 11, s = r & 2047;
                if (c < 2048) {
                    int hh = c >> 7, d = c & 127;
                    qo[(((size_t)(b * 16 + hh)) * 2048 + s) * 128 + d] = hv;
                } else if (c < 3072) {
                    int hh = (c - 2048) >> 7, d = c & 127;
                    ko[(((size_t)(b * 8 + hh)) * 2048 + s) * 128 + d] = hv;
                } else {
                    int hh = (c - 3072) >> 7, d = c & 127;
                    vto[(((size_t)(b * 8 + hh)) * 128 + d) * 2048 + s] = hv;
                }
            }
        }
    }
}

// ---------------- GEMM C = A * Bw^T (m97 structure) -- output projection ----------------
__global__ __launch_bounds__(256) void gemm_bt0(
    const u16* __restrict__ A, const u16* __restrict__ Bw, float* __restrict__ Cf, int N, int K) {
    __shared__ alignas(16) u16 As[128 * 32];
    __shared__ alignas(16) u16 Bs[128 * 32];
    int tid = threadIdx.x;
    int wid = tid >> 6, lane = tid & 63;
    int l16 = lane & 15, lhi = lane >> 4;
    int bm = blockIdx.y * 128, bn = blockIdx.x * 128;
    int wr = (wid >> 1) * 64, wc = (wid & 1) * 64;
    int srow = lane >> 2, sseg = lane & 3;
    f32x4 acc[4][4] = {};
    for (int kt = 0; kt < K; kt += 32) {
        __syncthreads();
#pragma unroll
        for (int i = 0; i < 2; ++i) {
            const u16* ga = A + (size_t)(bm + i * 64 + wid * 16 + srow) * K + kt + sseg * 8;
            GLDS16(ga, &As[(i * 64 + wid * 16) * 32]);
            const u16* gb = Bw + (size_t)(bn + i * 64 + wid * 16 + srow) * K + kt + sseg * 8;
            GLDS16(gb, &Bs[(i * 64 + wid * 16) * 32]);
        }
        __syncthreads();
        f16x8 af[4], bf[4];
#pragma unroll
        for (int mi = 0; mi < 4; ++mi) af[mi] = *(const f16x8*)&As[(wr + mi * 16 + l16) * 32 + lhi * 8];
#pragma unroll
        for (int ni = 0; ni < 4; ++ni) bf[ni] = *(const f16x8*)&Bs[(wc + ni * 16 + l16) * 32 + lhi * 8];
#pragma unroll
        for (int mi = 0; mi < 4; ++mi)
#pragma unroll
            for (int ni = 0; ni < 4; ++ni)
                acc[mi][ni] = __builtin_amdgcn_mfma_f32_16x16x32_f16(af[mi], bf[ni], acc[mi][ni], 0, 0, 0);
    }
#pragma unroll
    for (int mi = 0; mi < 4; ++mi)
#pragma unroll
        for (int ni = 0; ni < 4; ++ni)
#pragma unroll
            for (int j = 0; j < 4; ++j) {
                int r = bm + wr + mi * 16 + lhi * 4 + j;
                int c = bn + wc + ni * 16 + l16;
                Cf[(size_t)r * N + c] = acc[mi][ni][j];
            }
}

// ---------------- RoPE (in-place on f16 (B,nh,S,128)) ----------------
__global__ void rope_kernel(u16* __restrict__ t, const float* __restrict__ cosv,
                            const float* __restrict__ sinv, int nheads) {
    int i = blockIdx.x * 256 + threadIdx.x;
    int total = 2 * nheads * 2048 * 64;
    if (i >= total) return;
    int d = i & 63;
    int s = (i >> 6) & 2047;
    int bh = i >> 17;
    int b = bh / nheads;
    size_t base = ((size_t)bh * 2048 + s) * 128;
    size_t cb = ((size_t)b * 2048 + s) * 128;
    float x1 = h2f(t[base + d]), x2 = h2f(t[base + d + 64]);
    float c1 = cosv[cb + d], s1 = sinv[cb + d];
    float c2 = cosv[cb + d + 64], s2 = sinv[cb + d + 64];
    t[base + d] = f2h(x1 * c1 - x2 * s1);
    t[base + d + 64] = f2h(x2 * c2 + x1 * s2);
}

// ---------------- Wdtv = Wdt (16x1024) @ Wv (1024x2048), f32 ----------------
// one (h,c) per thread, serial-f summation (identical order to previous version -> same bits)
__global__ void wdtv_kernel(const float* __restrict__ Wdt, const float* __restrict__ Wv,
                            float* __restrict__ out) {
    int t = threadIdx.x;                  // 256
    int h = blockIdx.x >> 3;              // 0..15
    int c = (blockIdx.x & 7) * 256 + t;   // 0..2047
    const float* wd = Wdt + h * 1024;
    float acc = 0.f;
    for (int f = 0; f < 1024; ++f) acc += wd[f] * Wv[(size_t)f * 2048 + c];
    out[h * 2048 + c] = acc;
}

// ---------------- dt = x @ Wdtv^T ; dyn = exp(A*softplus(dt)), layout (B,H,S) f32 ----------------
__global__ void dt_dyn_kernel(const float* __restrict__ x, const float* __restrict__ Wdtv,
                              const float* __restrict__ Av, float* __restrict__ dyn) {
    __shared__ float xrow[2048];
    __shared__ float red[256];
    int bs = blockIdx.x;
    int t = threadIdx.x;
    for (int i = t; i < 2048; i += 256) xrow[i] = x[(size_t)bs * 2048 + i];
    __syncthreads();
    int h = t & 15, chunk = t >> 4;
    float p = 0.f;
    const float* wrow = Wdtv + h * 2048 + chunk * 128;
    const float* xr = xrow + chunk * 128;
    for (int f = 0; f < 128; ++f) p += xr[f] * wrow[f];
    red[t] = p;
    __syncthreads();
    if (t < 16) {
        float dt = 0.f;
        for (int c = 0; c < 16; ++c) dt += red[c * 16 + t];
        float sp = fmaxf(dt, 0.f) + log1pf(expf(-fabsf(dt)));
        int b = bs >> 11, s = bs & 2047;
        dyn[((size_t)(b * 16 + t)) * 2048 + s] = expf(Av[t] * sp);
    }
}

// ---------------- kth (1024th smallest of 2048) + mask values ----------------
__global__ void kth_mask_kernel(const float* __restrict__ dyn, float* __restrict__ mval) {
    __shared__ float sv[2048];
    int bh = blockIdx.x, t = threadIdx.x;  // 1024 threads
    const float* row = dyn + (size_t)bh * 2048;
    sv[t] = row[t];
    sv[t + 1024] = row[t + 1024];
    __syncthreads();
    for (int k = 2; k <= 2048; k <<= 1) {
        for (int j = k >> 1; j > 0; j >>= 1) {
#pragma unroll 1
            for (int base = 0; base < 2048; base += 1024) {
                int i = base + t;
                int ixj = i ^ j;
                if (ixj > i) {
                    float a = sv[i], b = sv[ixj];
                    bool up = ((i & k) == 0);
                    if ((a > b) == up) { sv[i] = b; sv[ixj] = a; }
                }
            }
            __syncthreads();
        }
    }
    float kth = sv[1023];
    float v0 = row[t];
    float v1 = row[t + 1024];
    mval[(size_t)bh * 2048 + t] = v0 < kth ? MINF : v0;
    mval[(size_t)bh * 2048 + t + 1024] = v1 < kth ? MINF : v1;
}

// ---------------- flash attention, causal + dynamic mask, GQA ----------------
// R9 changes: (a) softmax denominator via ones-column MFMA (accS) -- removes psum
// shuffle-reduce; (b) defer-max rescale with THR=8 (T13) -- skips accO/accS rescale
// and m update unless the running max moves by >8 (P bounded by e^8, fits f16).
__global__ __launch_bounds__(256) void attn_kernel(
    const u16* __restrict__ qb, const u16* __restrict__ kb, const u16* __restrict__ vtb,
    const float* __restrict__ mv, u16* __restrict__ ao) {
    __shared__ alignas(16) u16 Kst[2][64 * 128];
    __shared__ alignas(16) u16 Vst[2][128 * 64];
    __shared__ alignas(16) u16 plds[4][16 * 72];
    __shared__ int flags[4];
    int bh = blockIdx.x;
    int qt = 31 - blockIdx.y;
    int b = bh >> 4, h = bh & 15, kvh = h >> 1;
    int wid = threadIdx.x >> 6, lane = threadIdx.x & 63;
    int l16 = lane & 15, lhi = lane >> 4;
    int q0 = qt * 64 + wid * 16;
    const u16* qbase = qb + (((size_t)bh * 2048) + q0) * 128;
    const u16* kbase = kb + ((size_t)(b * 8 + kvh) * 2048) * 128;
    const u16* vtbase = vtb + ((size_t)(b * 8 + kvh) * 128) * 2048;
    const float* mvb = mv + (size_t)bh * 2048;
    u16* pw = plds[wid];
    int rx = l16 & 7;

    auto STAGE = [&](int kt2, int bidx) {
        int kvb2 = kt2 * 64;
#pragma unroll
        for (int i = 0; i < 4; ++i) {
            int call = wid * 4 + i;
            int r = call * 4 + (lane >> 4);
            int gch = (lane & 15) ^ (r & 7);
            const u16* src = kbase + (size_t)(kvb2 + r) * 128 + gch * 8;
            GLDS16(src, &Kst[bidx][call * 512]);
        }
#pragma unroll
        for (int i = 0; i < 4; ++i) {
            int call = wid * 4 + i;
            int d = call * 8 + (lane >> 3);
            int gch = (lane & 7) ^ (d & 7);
            const u16* src = vtbase + (size_t)d * 2048 + kvb2 + gch * 8;
            GLDS16(src, &Vst[bidx][call * 512]);
        }
    };

    f16x8 qf[4];
#pragma unroll
    for (int kc = 0; kc < 4; ++kc) qf[kc] = *(const f16x8*)&qbase[l16 * 128 + kc * 32 + lhi * 8];
    f16x8 ones;
#pragma unroll
    for (int i = 0; i < 8; ++i) ones[i] = (_Float16)1.f;
    float m[4];
#pragma unroll
    for (int j = 0; j < 4; ++j) m[j] = -INFINITY;
    f32x4 accO[8] = {};
    f32x4 accS = {};

    STAGE(0, 0);
    __syncthreads();

    for (int kt = 0; kt < 32; ++kt) {
        if (kt > qt) {
            if (!(flags[0] | flags[1] | flags[2] | flags[3])) break;
        }
        int buf = kt & 1;
        if (kt + 1 < 32) STAGE(kt + 1, buf ^ 1);
        int kvb = kt * 64;

        // QK^T from LDS (swizzled read)
        f32x4 sc[4] = {};
#pragma unroll
        for (int ni = 0; ni < 4; ++ni) {
            const u16* kr = &Kst[buf][(ni * 16 + l16) * 128];
#pragma unroll
            for (int kc = 0; kc < 4; ++kc) {
                int cc = (kc * 4 + lhi) ^ rx;
                f16x8 kf = *(const f16x8*)&kr[cc * 8];
                sc[ni] = __builtin_amdgcn_mfma_f32_16x16x32_f16(qf[kc], kf, sc[ni], 0, 0, 0);
            }
        }

        float rmax[4] = {-INFINITY, -INFINITY, -INFINITY, -INFINITY};
#pragma unroll
        for (int ni = 0; ni < 4; ++ni) {
            int key = kvb + ni * 16 + l16;
            float mk = mvb[key];
#pragma unroll
            for (int j = 0; j < 4; ++j) {
                int qrow = q0 + lhi * 4 + j;
                // exact reference arithmetic: mask = dynmask + causalMIN (f32, may -> -inf),
                // then score = qk*scale + mask (MIN absorbs qk*scale exactly).
                float sval = sc[ni][j] * SCALE + (mk + (key > qrow ? MINF : 0.f));
                sc[ni][j] = sval;
                rmax[j] = fmaxf(rmax[j], sval);
            }
        }
#pragma unroll
        for (int j = 0; j < 4; ++j) {
#pragma unroll
            for (int off = 1; off < 16; off <<= 1) rmax[j] = fmaxf(rmax[j], __shfl_xor(rmax[j], off));
        }
        // defer-max: only rescale when a row's max moved by > 8
        float mn[4];
        bool need = false;
#pragma unroll
        for (int j = 0; j < 4; ++j) {
            mn[j] = fmaxf(m[j], rmax[j]);
            need |= (mn[j] - m[j] > 8.0f);
        }
        if (__any(need)) {
#pragma unroll
            for (int j = 0; j < 4; ++j) {
                float r = __expf(m[j] - mn[j]);   // exp(0)=1 for unchanged rows
                m[j] = mn[j];
                accS[j] *= r;
#pragma unroll
                for (int db = 0; db < 8; ++db) accO[db][j] *= r;
            }
        }
#pragma unroll
        for (int ni = 0; ni < 4; ++ni) {
#pragma unroll
            for (int j = 0; j < 4; ++j) {
                float pv = __expf(sc[ni][j] - m[j]);   // bounded by e^8
                pw[(lhi * 4 + j) * 72 + ni * 16 + l16] = f2h(pv);
            }
        }

        // PV from LDS V (swizzled read) + ones-column row-sum into accS
#pragma unroll
        for (int kc2 = 0; kc2 < 2; ++kc2) {
            f16x8 pa = *(const f16x8*)&pw[l16 * 72 + kc2 * 32 + lhi * 8];
            accS = __builtin_amdgcn_mfma_f32_16x16x32_f16(pa, ones, accS, 0, 0, 0);
#pragma unroll
            for (int db = 0; db < 8; ++db) {
                int cc = (kc2 * 4 + lhi) ^ rx;
                f16x8 vf = *(const f16x8*)&Vst[buf][(db * 16 + l16) * 64 + cc * 8];
                accO[db] = __builtin_amdgcn_mfma_f32_16x16x32_f16(pa, vf, accO[db], 0, 0, 0);
            }
        }

        bool deg = (m[0] == MINF) | (m[1] == MINF) | (m[2] == MINF) | (m[3] == MINF);
        if (lane == 0) flags[wid] = __any(deg) ? 1 : 0;
        __syncthreads();
    }

#pragma unroll
    for (int db = 0; db < 8; ++db) {
#pragma unroll
        for (int j = 0; j < 4; ++j) {
            int qrow = q0 + lhi * 4 + j;
            int d = db * 16 + l16;
            float o = accO[db][j] / accS[j];
            ao[((size_t)(b * 2048) + qrow) * 2048 + h * 128 + d] = f2h(o);
        }
    }
}

extern "C" void kernel_launch(void* const* d_in, const int* in_sizes, int n_in,
                              void* d_out, int out_size, void* d_ws, size_t ws_size,
                              hipStream_t stream) {
    const float* x = (const float*)d_in[0];
    const float* cosv = (const float*)d_in[1];
    const float* sinv = (const float*)d_in[2];
    const float* Wq = (const float*)d_in[4];
    const float* Wk = (const float*)d_in[5];
    const float* Wv = (const float*)d_in[6];
    const float* Av = (const float*)d_in[7];
    const float* Wdt = (const float*)d_in[8];
    const float* Wo = (const float*)d_in[9];

    char* ws = (char*)d_ws;
    u16* qb = (u16*)(ws);
    u16* kb = (u16*)(ws + 16777216);
    u16* vtb = (u16*)(ws + 25165824);
    float* dyn = (float*)(ws + 33554432);
    float* mval = (float*)(ws + 33816576);
    float* wdtv = (float*)(ws + 34078720);
    u16* xbf = (u16*)(ws + 34209792);
    u16* wbf = (u16*)(ws + 50987008);

    // 1. conversions to f16
    convk8<<<8388608 / 2048, 256, 0, stream>>>(x, xbf, 8388608);
    convk8<<<4194304 / 2048, 256, 0, stream>>>(Wq, wbf, 4194304);
    convk8<<<2097152 / 2048, 256, 0, stream>>>(Wk, wbf + 4194304, 2097152);
    convk8<<<2097152 / 2048, 256, 0, stream>>>(Wv, wbf + 6291456, 2097152);

    // 2. fused QKV GEMM (256^2 tile, counted-vmcnt prefetch), scatter epilogue
    dim3 g1(16, 16);
    gemm8_qkv<<<g1, 512, 0, stream>>>(xbf, wbf, qb, kb, vtb);

    // 3. RoPE in-place on q and k
    rope_kernel<<<16384, 256, 0, stream>>>(qb, cosv, sinv, 16);
    rope_kernel<<<8192, 256, 0, stream>>>(kb, cosv, sinv, 8);

    // 4. dynamic mask path (f32-exact dt)
    wdtv_kernel<<<128, 256, 0, stream>>>(Wdt, Wv, wdtv);
    dt_dyn_kernel<<<4096, 256, 0, stream>>>(x, wdtv, Av, dyn);
    kth_mask_kernel<<<32, 1024, 0, stream>>>(dyn, mval);

    // 5. Wo -> f16
    convk8<<<4194304 / 2048, 256, 0, stream>>>(Wo, wbf, 4194304);

    // 6. attention
    dim3 g2(32, 32);
    attn_kernel<<<g2, 256, 0, stream>>>(qb, kb, vtb, mval, xbf);

    // 7. output projection -> f32 d_out
    dim3 g3(16, 32);
    gemm_bt0<<<g3, 256, 0, stream>>>(xbf, wbf, (float*)d_out, 2048, 2048);
}

// Round 11
// 446.704 us; speedup vs baseline: 1.7495x; 1.0366x over previous
//
#include <hip/hip_runtime.h>

typedef unsigned short u16;
typedef _Float16 f16x8 __attribute__((ext_vector_type(8)));
typedef float f32x4 __attribute__((ext_vector_type(4)));
typedef u16 u16x8 __attribute__((ext_vector_type(8)));

#define MINF (-0x1.fffffep+127f)
#define SCALE 0.08838834764831845f

__device__ __forceinline__ u16 f2h(float f) {
    _Float16 h = (_Float16)f;
    return __builtin_bit_cast(u16, h);
}
__device__ __forceinline__ float h2f(u16 u) {
    _Float16 h = __builtin_bit_cast(_Float16, u);
    return (float)h;
}

typedef const __attribute__((address_space(1))) void* gptr_t;
typedef __attribute__((address_space(3))) void* sptr_t;
#define GLDS16(g, l) __builtin_amdgcn_global_load_lds((gptr_t)(const void*)(g), (sptr_t)(void*)(l), 16, 0, 0)

// ---------------- f32 -> f16 conversion, 8 elem/thread (n must be divisible by 2048) ----------------
__global__ void convk8(const float* __restrict__ in, u16* __restrict__ out, int n) {
    int i = (blockIdx.x * 256 + threadIdx.x) * 8;
    if (i >= n) return;
    f32x4 a = *(const f32x4*)&in[i];
    f32x4 b = *(const f32x4*)&in[i + 4];
    u16x8 r;
#pragma unroll
    for (int j = 0; j < 4; ++j) { r[j] = f2h(a[j]); r[j + 4] = f2h(b[j]); }
    *(u16x8*)&out[i] = r;
}

// ---------------- QKV GEMM, 256x256 tile, BK=64, 8 waves, counted-vmcnt prefetch ----------------
__global__ __launch_bounds__(512, 1) void gemm8_qkv(
    const u16* __restrict__ A, const u16* __restrict__ Bw,
    u16* __restrict__ qo, u16* __restrict__ ko, u16* __restrict__ vto) {
    __shared__ alignas(16) u16 AS[2][2][128 * 64];
    __shared__ alignas(16) u16 BS[2][2][128 * 64];
    const int K = 2048, NT = 32;
    int tid = threadIdx.x;
    int wid = tid >> 6, lane = tid & 63;
    int l16 = lane & 15, lhi = lane >> 4;
    int wm = wid >> 2, wn = wid & 3;
    int bm = blockIdx.y * 256, bn = blockIdx.x * 256;
    int srow = lane >> 3;
    int schunk = (lane & 7) ^ srow;
    f32x4 acc[8][4] = {};

    auto STAGE = [&](int t, int buf) {
        int kt = t * 64;
#pragma unroll
        for (int i = 0; i < 2; ++i) {
            int c = wid * 2 + i;
            int row = c * 8 + srow;
            const u16* sa0 = A + (size_t)(bm + row) * K + kt + schunk * 8;
            GLDS16(sa0, &AS[buf][0][c * 512]);
            const u16* sa1 = A + (size_t)(bm + 128 + row) * K + kt + schunk * 8;
            GLDS16(sa1, &AS[buf][1][c * 512]);
            const u16* sb0 = Bw + (size_t)(bn + row) * K + kt + schunk * 8;
            GLDS16(sb0, &BS[buf][0][c * 512]);
            const u16* sb1 = Bw + (size_t)(bn + 128 + row) * K + kt + schunk * 8;
            GLDS16(sb1, &BS[buf][1][c * 512]);
        }
    };

    auto COMPUTE = [&](int buf) {
#pragma unroll
        for (int kk = 0; kk < 2; ++kk) {
            f16x8 af[8], bf[4];
#pragma unroll
            for (int ni = 0; ni < 4; ++ni) {
                int rb = wn * 64 + ni * 16 + l16;
                int half = rb >> 7, rh = rb & 127;
                int c2 = (kk * 4 + lhi) ^ (rh & 7);
                bf[ni] = *(const f16x8*)&BS[buf][half][rh * 64 + c2 * 8];
            }
#pragma unroll
            for (int mi = 0; mi < 8; ++mi) {
                int rh = mi * 16 + l16;
                int c2 = (kk * 4 + lhi) ^ (rh & 7);
                af[mi] = *(const f16x8*)&AS[buf][wm][rh * 64 + c2 * 8];
            }
            __builtin_amdgcn_s_setprio(1);
#pragma unroll
            for (int mi = 0; mi < 8; ++mi)
#pragma unroll
                for (int ni = 0; ni < 4; ++ni)
                    acc[mi][ni] = __builtin_amdgcn_mfma_f32_16x16x32_f16(af[mi], bf[ni], acc[mi][ni], 0, 0, 0);
            __builtin_amdgcn_s_setprio(0);
        }
    };

    STAGE(0, 0);
    STAGE(1, 1);
    asm volatile("s_waitcnt vmcnt(8)" ::: "memory");
    __builtin_amdgcn_sched_barrier(0);
    __builtin_amdgcn_s_barrier();

    for (int t = 0; t < NT; ++t) {
        int buf = t & 1;
        COMPUTE(buf);
        __builtin_amdgcn_s_barrier();
        if (t + 2 < NT) {
            STAGE(t + 2, buf);
            asm volatile("s_waitcnt vmcnt(8)" ::: "memory");
        } else {
            asm volatile("s_waitcnt vmcnt(0)" ::: "memory");
        }
        __builtin_amdgcn_sched_barrier(0);
        __builtin_amdgcn_s_barrier();
    }

#pragma unroll
    for (int mi = 0; mi < 8; ++mi) {
#pragma unroll
        for (int ni = 0; ni < 4; ++ni) {
#pragma unroll
            for (int j = 0; j < 4; ++j) {
                int r = bm + wm * 128 + mi * 16 + lhi * 4 + j;
                int c = bn + wn * 64 + ni * 16 + l16;
                u16 hv = f2h(acc[mi][ni][j]);
                int b = r >> 11, s = r & 2047;
                if (c < 2048) {
                    int hh = c >> 7, d = c & 127;
                    qo[(((size_t)(b * 16 + hh)) * 2048 + s) * 128 + d] = hv;
                } else if (c < 3072) {
                    int hh = (c - 2048) >> 7, d = c & 127;
                    ko[(((size_t)(b * 8 + hh)) * 2048 + s) * 128 + d] = hv;
                } else {
                    int hh = (c - 3072) >> 7, d = c & 127;
                    vto[(((size_t)(b * 8 + hh)) * 128 + d) * 2048 + s] = hv;
                }
            }
        }
    }
}

// ---------------- Output projection, 256x128 tile, BK=64, 8 waves, counted-vmcnt ----------------
// C (4096x2048 f32) = A (4096x2048 f16) * Bw^T (2048x2048 f16). Grid 16x16 = 256 blocks = 1/CU.
// Per wave: 128x32 output (mi 8 x ni 2). 6 GLDS/wave/tile -> steady-state vmcnt(6).
// K-chunk accumulation order identical to the old 128^2 kernel -> bit-identical C.
__global__ __launch_bounds__(512, 1) void gemm8_op(
    const u16* __restrict__ A, const u16* __restrict__ Bw, float* __restrict__ Cf) {
    __shared__ alignas(16) u16 AS[2][2][128 * 64];
    __shared__ alignas(16) u16 BS[2][128 * 64];
    const int K = 2048, NT = 32;
    int tid = threadIdx.x;
    int wid = tid >> 6, lane = tid & 63;
    int l16 = lane & 15, lhi = lane >> 4;
    int wm = wid >> 2, wn = wid & 3;
    int bm = blockIdx.y * 256, bn = blockIdx.x * 128;
    int srow = lane >> 3;
    int schunk = (lane & 7) ^ srow;
    f32x4 acc[8][2] = {};

    auto STAGE = [&](int t, int buf) {
        int kt = t * 64;
#pragma unroll
        for (int i = 0; i < 2; ++i) {
            int c = wid * 2 + i;
            int row = c * 8 + srow;
            const u16* sa0 = A + (size_t)(bm + row) * K + kt + schunk * 8;
            GLDS16(sa0, &AS[buf][0][c * 512]);
            const u16* sa1 = A + (size_t)(bm + 128 + row) * K + kt + schunk * 8;
            GLDS16(sa1, &AS[buf][1][c * 512]);
            const u16* sb0 = Bw + (size_t)(bn + row) * K + kt + schunk * 8;
            GLDS16(sb0, &BS[buf][c * 512]);
        }
    };

    auto COMPUTE = [&](int buf) {
#pragma unroll
        for (int kk = 0; kk < 2; ++kk) {
            f16x8 af[8], bf[2];
#pragma unroll
            for (int ni = 0; ni < 2; ++ni) {
                int rb = wn * 32 + ni * 16 + l16;      // 0..127
                int c2 = (kk * 4 + lhi) ^ (rb & 7);
                bf[ni] = *(const f16x8*)&BS[buf][rb * 64 + c2 * 8];
            }
#pragma unroll
            for (int mi = 0; mi < 8; ++mi) {
                int rh = mi * 16 + l16;
                int c2 = (kk * 4 + lhi) ^ (rh & 7);
                af[mi] = *(const f16x8*)&AS[buf][wm][rh * 64 + c2 * 8];
            }
            __builtin_amdgcn_s_setprio(1);
#pragma unroll
            for (int mi = 0; mi < 8; ++mi)
#pragma unroll
                for (int ni = 0; ni < 2; ++ni)
                    acc[mi][ni] = __builtin_amdgcn_mfma_f32_16x16x32_f16(af[mi], bf[ni], acc[mi][ni], 0, 0, 0);
            __builtin_amdgcn_s_setprio(0);
        }
    };

    STAGE(0, 0);
    STAGE(1, 1);
    asm volatile("s_waitcnt vmcnt(6)" ::: "memory");
    __builtin_amdgcn_sched_barrier(0);
    __builtin_amdgcn_s_barrier();

    for (int t = 0; t < NT; ++t) {
        int buf = t & 1;
        COMPUTE(buf);
        __builtin_amdgcn_s_barrier();
        if (t + 2 < NT) {
            STAGE(t + 2, buf);
            asm volatile("s_waitcnt vmcnt(6)" ::: "memory");
        } else {
            asm volatile("s_waitcnt vmcnt(0)" ::: "memory");
        }
        __builtin_amdgcn_sched_barrier(0);
        __builtin_amdgcn_s_barrier();
    }

#pragma unroll
    for (int mi = 0; mi < 8; ++mi)
#pragma unroll
        for (int ni = 0; ni < 2; ++ni)
#pragma unroll
            for (int j = 0; j < 4; ++j) {
                int r = bm + wm * 128 + mi * 16 + lhi * 4 + j;
                int c = bn + wn * 32 + ni * 16 + l16;
                Cf[(size_t)r * 2048 + c] = acc[mi][ni][j];
            }
}

// ---------------- RoPE fused q+k: one thread per (b,s,d<64), cos/sin loaded once ----------------
__global__ void rope_fused(u16* __restrict__ q, u16* __restrict__ k,
                           const float* __restrict__ cosv, const float* __restrict__ sinv) {
    int i = blockIdx.x * 256 + threadIdx.x;   // 2*2048*64 = 262144 threads
    int d = i & 63;
    int s = (i >> 6) & 2047;
    int b = i >> 17;
    size_t cb = ((size_t)b * 2048 + s) * 128;
    float c1 = cosv[cb + d], s1 = sinv[cb + d];
    float c2 = cosv[cb + d + 64], s2 = sinv[cb + d + 64];
#pragma unroll
    for (int h = 0; h < 16; ++h) {
        size_t base = (((size_t)(b * 16 + h)) * 2048 + s) * 128;
        float x1 = h2f(q[base + d]), x2 = h2f(q[base + d + 64]);
        q[base + d] = f2h(x1 * c1 - x2 * s1);
        q[base + d + 64] = f2h(x2 * c2 + x1 * s2);
    }
#pragma unroll
    for (int h = 0; h < 8; ++h) {
        size_t base = (((size_t)(b * 8 + h)) * 2048 + s) * 128;
        float x1 = h2f(k[base + d]), x2 = h2f(k[base + d + 64]);
        k[base + d] = f2h(x1 * c1 - x2 * s1);
        k[base + d + 64] = f2h(x2 * c2 + x1 * s2);
    }
}

// ---------------- Wdtv = Wdt (16x1024) @ Wv (1024x2048), f32 ----------------
__global__ void wdtv_kernel(const float* __restrict__ Wdt, const float* __restrict__ Wv,
                            float* __restrict__ out) {
    int t = threadIdx.x;                  // 256
    int h = blockIdx.x >> 3;              // 0..15
    int c = (blockIdx.x & 7) * 256 + t;   // 0..2047
    const float* wd = Wdt + h * 1024;
    float acc = 0.f;
    for (int f = 0; f < 1024; ++f) acc += wd[f] * Wv[(size_t)f * 2048 + c];
    out[h * 2048 + c] = acc;
}

// ---------------- dt = x @ Wdtv^T ; dyn = exp(A*softplus(dt)), layout (B,H,S) f32 ----------------
__global__ void dt_dyn_kernel(const float* __restrict__ x, const float* __restrict__ Wdtv,
                              const float* __restrict__ Av, float* __restrict__ dyn) {
    __shared__ float xrow[2048];
    __shared__ float red[256];
    int bs = blockIdx.x;
    int t = threadIdx.x;
    for (int i = t; i < 2048; i += 256) xrow[i] = x[(size_t)bs * 2048 + i];
    __syncthreads();
    int h = t & 15, chunk = t >> 4;
    float p = 0.f;
    const float* wrow = Wdtv + h * 2048 + chunk * 128;
    const float* xr = xrow + chunk * 128;
    for (int f = 0; f < 128; ++f) p += xr[f] * wrow[f];
    red[t] = p;
    __syncthreads();
    if (t < 16) {
        float dt = 0.f;
        for (int c = 0; c < 16; ++c) dt += red[c * 16 + t];
        float sp = fmaxf(dt, 0.f) + log1pf(expf(-fabsf(dt)));
        int b = bs >> 11, s = bs & 2047;
        dyn[((size_t)(b * 16 + t)) * 2048 + s] = expf(Av[t] * sp);
    }
}

// ---------------- kth (1024th smallest of 2048) + mask values ----------------
__global__ void kth_mask_kernel(const float* __restrict__ dyn, float* __restrict__ mval) {
    __shared__ float sv[2048];
    int bh = blockIdx.x, t = threadIdx.x;  // 1024 threads
    const float* row = dyn + (size_t)bh * 2048;
    sv[t] = row[t];
    sv[t + 1024] = row[t + 1024];
    __syncthreads();
    for (int k = 2; k <= 2048; k <<= 1) {
        for (int j = k >> 1; j > 0; j >>= 1) {
#pragma unroll 1
            for (int base = 0; base < 2048; base += 1024) {
                int i = base + t;
                int ixj = i ^ j;
                if (ixj > i) {
                    float a = sv[i], b = sv[ixj];
                    bool up = ((i & k) == 0);
                    if ((a > b) == up) { sv[i] = b; sv[ixj] = a; }
                }
            }
            __syncthreads();
        }
    }
    float kth = sv[1023];
    float v0 = row[t];
    float v1 = row[t + 1024];
    mval[(size_t)bh * 2048 + t] = v0 < kth ? MINF : v0;
    mval[(size_t)bh * 2048 + t + 1024] = v1 < kth ? MINF : v1;
}

// ---------------- flash attention, causal + dynamic mask, GQA (unchanged from R10) ----------------
__global__ __launch_bounds__(256) void attn_kernel(
    const u16* __restrict__ qb, const u16* __restrict__ kb, const u16* __restrict__ vtb,
    const float* __restrict__ mv, u16* __restrict__ ao) {
    __shared__ alignas(16) u16 Kst[2][64 * 128];
    __shared__ alignas(16) u16 Vst[2][128 * 64];
    __shared__ alignas(16) u16 plds[4][16 * 72];
    __shared__ int flags[4];
    int bh = blockIdx.x;
    int qt = 31 - blockIdx.y;
    int b = bh >> 4, h = bh & 15, kvh = h >> 1;
    int wid = threadIdx.x >> 6, lane = threadIdx.x & 63;
    int l16 = lane & 15, lhi = lane >> 4;
    int q0 = qt * 64 + wid * 16;
    const u16* qbase = qb + (((size_t)bh * 2048) + q0) * 128;
    const u16* kbase = kb + ((size_t)(b * 8 + kvh) * 2048) * 128;
    const u16* vtbase = vtb + ((size_t)(b * 8 + kvh) * 128) * 2048;
    const float* mvb = mv + (size_t)bh * 2048;
    u16* pw = plds[wid];
    int rx = l16 & 7;

    auto STAGE = [&](int kt2, int bidx) {
        int kvb2 = kt2 * 64;
#pragma unroll
        for (int i = 0; i < 4; ++i) {
            int call = wid * 4 + i;
            int r = call * 4 + (lane >> 4);
            int gch = (lane & 15) ^ (r & 7);
            const u16* src = kbase + (size_t)(kvb2 + r) * 128 + gch * 8;
            GLDS16(src, &Kst[bidx][call * 512]);
        }
#pragma unroll
        for (int i = 0; i < 4; ++i) {
            int call = wid * 4 + i;
            int d = call * 8 + (lane >> 3);
            int gch = (lane & 7) ^ (d & 7);
            const u16* src = vtbase + (size_t)d * 2048 + kvb2 + gch * 8;
            GLDS16(src, &Vst[bidx][call * 512]);
        }
    };

    f16x8 qf[4];
#pragma unroll
    for (int kc = 0; kc < 4; ++kc) qf[kc] = *(const f16x8*)&qbase[l16 * 128 + kc * 32 + lhi * 8];
    f16x8 ones;
#pragma unroll
    for (int i = 0; i < 8; ++i) ones[i] = (_Float16)1.f;
    float m[4];
#pragma unroll
    for (int j = 0; j < 4; ++j) m[j] = -INFINITY;
    f32x4 accO[8] = {};
    f32x4 accS = {};

    STAGE(0, 0);
    __syncthreads();

    for (int kt = 0; kt < 32; ++kt) {
        if (kt > qt) {
            if (!(flags[0] | flags[1] | flags[2] | flags[3])) break;
        }
        int buf = kt & 1;
        if (kt + 1 < 32) STAGE(kt + 1, buf ^ 1);
        int kvb = kt * 64;

        f32x4 sc[4] = {};
#pragma unroll
        for (int ni = 0; ni < 4; ++ni) {
            const u16* kr = &Kst[buf][(ni * 16 + l16) * 128];
#pragma unroll
            for (int kc = 0; kc < 4; ++kc) {
                int cc = (kc * 4 + lhi) ^ rx;
                f16x8 kf = *(const f16x8*)&kr[cc * 8];
                sc[ni] = __builtin_amdgcn_mfma_f32_16x16x32_f16(qf[kc], kf, sc[ni], 0, 0, 0);
            }
        }

        float rmax[4] = {-INFINITY, -INFINITY, -INFINITY, -INFINITY};
#pragma unroll
        for (int ni = 0; ni < 4; ++ni) {
            int key = kvb + ni * 16 + l16;
            float mk = mvb[key];
#pragma unroll
            for (int j = 0; j < 4; ++j) {
                int qrow = q0 + lhi * 4 + j;
                float sval = sc[ni][j] * SCALE + (mk + (key > qrow ? MINF : 0.f));
                sc[ni][j] = sval;
                rmax[j] = fmaxf(rmax[j], sval);
            }
        }
#pragma unroll
        for (int j = 0; j < 4; ++j) {
#pragma unroll
            for (int off = 1; off < 16; off <<= 1) rmax[j] = fmaxf(rmax[j], __shfl_xor(rmax[j], off));
        }
        float mn[4];
        bool need = false;
#pragma unroll
        for (int j = 0; j < 4; ++j) {
            mn[j] = fmaxf(m[j], rmax[j]);
            need |= (mn[j] - m[j] > 8.0f);
        }
        if (__any(need)) {
#pragma unroll
            for (int j = 0; j < 4; ++j) {
                float r = __expf(m[j] - mn[j]);
                m[j] = mn[j];
                accS[j] *= r;
#pragma unroll
                for (int db = 0; db < 8; ++db) accO[db][j] *= r;
            }
        }
#pragma unroll
        for (int ni = 0; ni < 4; ++ni) {
#pragma unroll
            for (int j = 0; j < 4; ++j) {
                float pv = __expf(sc[ni][j] - m[j]);
                pw[(lhi * 4 + j) * 72 + ni * 16 + l16] = f2h(pv);
            }
        }

#pragma unroll
        for (int kc2 = 0; kc2 < 2; ++kc2) {
            f16x8 pa = *(const f16x8*)&pw[l16 * 72 + kc2 * 32 + lhi * 8];
            accS = __builtin_amdgcn_mfma_f32_16x16x32_f16(pa, ones, accS, 0, 0, 0);
#pragma unroll
            for (int db = 0; db < 8; ++db) {
                int cc = (kc2 * 4 + lhi) ^ rx;
                f16x8 vf = *(const f16x8*)&Vst[buf][(db * 16 + l16) * 64 + cc * 8];
                accO[db] = __builtin_amdgcn_mfma_f32_16x16x32_f16(pa, vf, accO[db], 0, 0, 0);
            }
        }

        bool deg = (m[0] == MINF) | (m[1] == MINF) | (m[2] == MINF) | (m[3] == MINF);
        if (lane == 0) flags[wid] = __any(deg) ? 1 : 0;
        __syncthreads();
    }

#pragma unroll
    for (int db = 0; db < 8; ++db) {
#pragma unroll
        for (int j = 0; j < 4; ++j) {
            int qrow = q0 + lhi * 4 + j;
            int d = db * 16 + l16;
            float o = accO[db][j] / accS[j];
            ao[((size_t)(b * 2048) + qrow) * 2048 + h * 128 + d] = f2h(o);
        }
    }
}

extern "C" void kernel_launch(void* const* d_in, const int* in_sizes, int n_in,
                              void* d_out, int out_size, void* d_ws, size_t ws_size,
                              hipStream_t stream) {
    const float* x = (const float*)d_in[0];
    const float* cosv = (const float*)d_in[1];
    const float* sinv = (const float*)d_in[2];
    const float* Wq = (const float*)d_in[4];
    const float* Wk = (const float*)d_in[5];
    const float* Wv = (const float*)d_in[6];
    const float* Av = (const float*)d_in[7];
    const float* Wdt = (const float*)d_in[8];
    const float* Wo = (const float*)d_in[9];

    char* ws = (char*)d_ws;
    u16* qb = (u16*)(ws);
    u16* kb = (u16*)(ws + 16777216);
    u16* vtb = (u16*)(ws + 25165824);
    float* dyn = (float*)(ws + 33554432);
    float* mval = (float*)(ws + 33816576);
    float* wdtv = (float*)(ws + 34078720);
    u16* xbf = (u16*)(ws + 34209792);
    u16* wbf = (u16*)(ws + 50987008);

    // 1. conversions to f16
    convk8<<<8388608 / 2048, 256, 0, stream>>>(x, xbf, 8388608);
    convk8<<<4194304 / 2048, 256, 0, stream>>>(Wq, wbf, 4194304);
    convk8<<<2097152 / 2048, 256, 0, stream>>>(Wk, wbf + 4194304, 2097152);
    convk8<<<2097152 / 2048, 256, 0, stream>>>(Wv, wbf + 6291456, 2097152);

    // 2. fused QKV GEMM (256^2 tile, counted-vmcnt prefetch), scatter epilogue
    dim3 g1(16, 16);
    gemm8_qkv<<<g1, 512, 0, stream>>>(xbf, wbf, qb, kb, vtb);

    // 3. RoPE fused q+k (cos/sin loaded once per (b,s,d))
    rope_fused<<<1024, 256, 0, stream>>>(qb, kb, cosv, sinv);

    // 4. dynamic mask path (f32-exact dt)
    wdtv_kernel<<<128, 256, 0, stream>>>(Wdt, Wv, wdtv);
    dt_dyn_kernel<<<4096, 256, 0, stream>>>(x, wdtv, Av, dyn);
    kth_mask_kernel<<<32, 1024, 0, stream>>>(dyn, mval);

    // 5. Wo -> f16
    convk8<<<4194304 / 2048, 256, 0, stream>>>(Wo, wbf, 4194304);

    // 6. attention
    dim3 g2(32, 32);
    attn_kernel<<<g2, 256, 0, stream>>>(qb, kb, vtb, mval, xbf);

    // 7. output projection (256x128 tile, counted-vmcnt) -> f32 d_out
    dim3 g3(16, 16);
    gemm8_op<<<g3, 512, 0, stream>>>(xbf, wbf, (float*)d_out);
}